// Round 18
// baseline (435.191 us; speedup 1.0000x reference)
//
#include <hip/hip_runtime.h>
#include <float.h>

// B=1, S=2048, D=2048, H=16, HD=128, HV=4, R=128, NV=2048, K=4
#define NEG_MIN (-3.4028234663852886e38f)
#define INV_SQRT_HD 0.08838834764831845f
#define SCALE_L2E 0.12751791437968458f    // INV_SQRT_HD * log2(e)

typedef __attribute__((ext_vector_type(8))) short bf16x8;
typedef __attribute__((ext_vector_type(8))) unsigned short u16x8;
typedef __attribute__((ext_vector_type(4))) float f32x4;

__device__ __forceinline__ void gload_lds16(const void* g, void* l) {
  __builtin_amdgcn_global_load_lds((const __attribute__((address_space(1))) void*)g,
                                   (__attribute__((address_space(3))) void*)l, 16, 0, 0);
}
__device__ __forceinline__ ushort f2bf(float x) {
  union { float f; unsigned u; } v; v.f = x;
  unsigned r = v.u + 0x7fffu + ((v.u >> 16) & 1u);   // RNE
  return (ushort)(r >> 16);
}
__device__ __forceinline__ float bf2f(ushort u) {
  union { unsigned i; float f; } v; v.i = ((unsigned)u) << 16; return v.f;
}
template<int CTRL>
__device__ __forceinline__ float dpp_ror(float x) {
  return __int_as_float(__builtin_amdgcn_mov_dpp(__float_as_int(x), CTRL, 0xF, 0xF, true));
}
template<int CTRL>
__device__ __forceinline__ unsigned dpp_ror_u(unsigned x) {
  return (unsigned)__builtin_amdgcn_mov_dpp((int)x, CTRL, 0xF, 0xF, true);
}
__device__ __forceinline__ unsigned wave_umax64(unsigned x) {
  x = max(x, dpp_ror_u<0x121>(x));
  x = max(x, dpp_ror_u<0x122>(x));
  x = max(x, dpp_ror_u<0x124>(x));
  x = max(x, dpp_ror_u<0x128>(x));
  x = max(x, (unsigned)__shfl_xor((int)x, 16));
  x = max(x, (unsigned)__shfl_xor((int)x, 32));
  return x;
}
__device__ __forceinline__ unsigned bf_sortable(ushort b) {
  return (b & 0x8000u) ? (unsigned)(b ^ 0xFFFFu) : (unsigned)(b | 0x8000u);
}

// ---------------------------------------------------------------------------
// vq via 3-term bf16 emulation of f32 GEMM (MFMA pipe, rel err ~8e-6)
// ---------------------------------------------------------------------------
__global__ __launch_bounds__(256) void gemm_vq3(
    const ushort* __restrict__ Ah, const ushort* __restrict__ Al, int lda,
    const ushort* __restrict__ Bh, const ushort* __restrict__ Bl, int ldb,
    float* __restrict__ Cp, int ldc, int Kchunk)
{
  __shared__ ushort sAh[128 * 64], sAl[128 * 64];
  __shared__ ushort sBh[128 * 64], sBl[128 * 64];
  const int t = threadIdx.x, w = t >> 6, lane = t & 63;
  const int lr = lane & 15, lk = lane >> 4;
  const int bm = blockIdx.y << 7, bn = blockIdx.x << 7;
  const int k0base = blockIdx.z * Kchunk;
  const int wm = (w >> 1) << 6, wn = (w & 1) << 6;
  f32x4 acc[4][4];
#pragma unroll
  for (int i = 0; i < 4; ++i)
#pragma unroll
    for (int j = 0; j < 4; ++j) acc[i][j] = (f32x4){0.f, 0.f, 0.f, 0.f};

  for (int k0 = 0; k0 < Kchunk; k0 += 64) {
    const int kg = k0base + k0;
    __syncthreads();
#pragma unroll
    for (int qI = 0; qI < 4; ++qI) {
      int b = w * 4096 + qI * 1024 + lane * 16;
      int row = b >> 7, colb = b & 127;
      int src = colb ^ ((row & 7) << 4);
      gload_lds16((const char*)Ah + ((size_t)(bm + row) * lda + kg) * 2 + src,
                  (char*)sAh + w * 4096 + qI * 1024);
      gload_lds16((const char*)Al + ((size_t)(bm + row) * lda + kg) * 2 + src,
                  (char*)sAl + w * 4096 + qI * 1024);
      gload_lds16((const char*)Bh + ((size_t)(bn + row) * ldb + kg) * 2 + src,
                  (char*)sBh + w * 4096 + qI * 1024);
      gload_lds16((const char*)Bl + ((size_t)(bn + row) * ldb + kg) * 2 + src,
                  (char*)sBl + w * 4096 + qI * 1024);
    }
    __syncthreads();
#pragma unroll
    for (int kk = 0; kk < 2; ++kk) {
      bf16x8 ah[4], al[4], bh[4], bl[4];
#pragma unroll
      for (int mi = 0; mi < 4; ++mi) {
        int row = wm + mi * 16 + lr;
        int off = row * 128 + ((kk * 64 + lk * 16) ^ ((row & 7) << 4));
        ah[mi] = *(const bf16x8*)((const char*)sAh + off);
        al[mi] = *(const bf16x8*)((const char*)sAl + off);
      }
#pragma unroll
      for (int ni = 0; ni < 4; ++ni) {
        int row = wn + ni * 16 + lr;
        int off = row * 128 + ((kk * 64 + lk * 16) ^ ((row & 7) << 4));
        bh[ni] = *(const bf16x8*)((const char*)sBh + off);
        bl[ni] = *(const bf16x8*)((const char*)sBl + off);
      }
#pragma unroll
      for (int mi = 0; mi < 4; ++mi)
#pragma unroll
        for (int ni = 0; ni < 4; ++ni) {
          acc[mi][ni] = __builtin_amdgcn_mfma_f32_16x16x32_bf16(ah[mi], bh[ni], acc[mi][ni], 0, 0, 0);
          acc[mi][ni] = __builtin_amdgcn_mfma_f32_16x16x32_bf16(ah[mi], bl[ni], acc[mi][ni], 0, 0, 0);
          acc[mi][ni] = __builtin_amdgcn_mfma_f32_16x16x32_bf16(al[mi], bh[ni], acc[mi][ni], 0, 0, 0);
        }
    }
  }
  float* C = Cp + (size_t)blockIdx.z * 1048576;
#pragma unroll
  for (int mi = 0; mi < 4; ++mi)
#pragma unroll
    for (int j = 0; j < 4; ++j) {
      int row = bm + wm + mi * 16 + lk * 4 + j;
#pragma unroll
      for (int ni = 0; ni < 4; ++ni)
        C[(size_t)row * ldc + bn + wn + ni * 16 + lr] = acc[mi][ni][j];
    }
}

// deterministic 8-way reduce of split-K partials + bf16 copy (1M floats)
__global__ __launch_bounds__(256) void reduce8_cvt(const float* __restrict__ Cp,
    float* __restrict__ vq, ushort* __restrict__ vq_bf)
{
  int i = (blockIdx.x * 256 + threadIdx.x) << 2;
  float4 s = make_float4(0.f, 0.f, 0.f, 0.f);
#pragma unroll
  for (int z = 0; z < 8; ++z) {
    float4 a = *(const float4*)(Cp + (size_t)z * 1048576 + i);
    s.x += a.x; s.y += a.y; s.z += a.z; s.w += a.w;
  }
  *(float4*)(vq + i) = s;
  ushort4 o; o.x = f2bf(s.x); o.y = f2bf(s.y); o.z = f2bf(s.z); o.w = f2bf(s.w);
  *(ushort4*)(vq_bf + i) = o;
}

// ---------------------------------------------------------------------------
// bf16 MFMA GEMM (z-batched): C = A @ Bt^T. 128x128 tile, BK=64.
// 2-phase double-buffered LDS. ROPE=1: fused RoPE epilogue for bn<16.
// ---------------------------------------------------------------------------
template<int OUT_BF16, int ROPE>
__global__ __launch_bounds__(256) void gemm_bf16(
    const ushort* __restrict__ A0, int lda,
    const ushort* __restrict__ Bt0, int ldb,
    void* __restrict__ C0, int ldc, int Kd,
    size_t strA, size_t strB, size_t strC,
    const float* __restrict__ cosb, const float* __restrict__ sinb)
{
  const ushort* A  = A0  + blockIdx.z * strA;
  const ushort* Bt = Bt0 + blockIdx.z * strB;
  __shared__ ushort As[2][128 * 64];
  __shared__ ushort Bs[2][128 * 64];
  const int t = threadIdx.x, w = t >> 6, lane = t & 63;
  const int lr = lane & 15, lk = lane >> 4;
  const int bm = blockIdx.y << 7, bn = blockIdx.x << 7;
  const int wm = (w >> 1) << 6, wn = (w & 1) << 6;
  f32x4 acc[4][4];
#pragma unroll
  for (int i = 0; i < 4; ++i)
#pragma unroll
    for (int j = 0; j < 4; ++j) acc[i][j] = (f32x4){0.f, 0.f, 0.f, 0.f};

#define STAGE_QK(buf, kk0)                                                     \
  {                                                                            \
_Pragma("unroll")                                                              \
    for (int qI = 0; qI < 4; ++qI) {                                           \
      int b = w * 4096 + qI * 1024 + lane * 16;                                \
      int row = b >> 7, colb = b & 127;                                        \
      int src = colb ^ ((row & 7) << 4);                                       \
      gload_lds16((const char*)A + ((size_t)(bm + row) * lda + (kk0)) * 2 + src,\
                  (char*)As[buf] + w * 4096 + qI * 1024);                      \
      gload_lds16((const char*)Bt + ((size_t)(bn + row) * ldb + (kk0)) * 2 + src,\
                  (char*)Bs[buf] + w * 4096 + qI * 1024);                      \
    }                                                                          \
  }

  STAGE_QK(0, 0);
  int cur = 0;
  for (int k0 = 0; k0 < Kd; k0 += 64) {
    __syncthreads();
    if (k0 + 64 < Kd) STAGE_QK(cur ^ 1, k0 + 64);
#pragma unroll
    for (int kk = 0; kk < 2; ++kk) {
      bf16x8 af[4], bf[4];
#pragma unroll
      for (int mi = 0; mi < 4; ++mi) {
        int row = wm + mi * 16 + lr;
        af[mi] = *(const bf16x8*)((const char*)As[cur] + row * 128 + ((kk * 64 + lk * 16) ^ ((row & 7) << 4)));
      }
#pragma unroll
      for (int ni = 0; ni < 4; ++ni) {
        int row = wn + ni * 16 + lr;
        bf[ni] = *(const bf16x8*)((const char*)Bs[cur] + row * 128 + ((kk * 64 + lk * 16) ^ ((row & 7) << 4)));
      }
#pragma unroll
      for (int mi = 0; mi < 4; ++mi)
#pragma unroll
        for (int ni = 0; ni < 4; ++ni)
          acc[mi][ni] = __builtin_amdgcn_mfma_f32_16x16x32_bf16(af[mi], bf[ni], acc[mi][ni], 0, 0, 0);
    }
    cur ^= 1;
  }
#undef STAGE_QK

  if (ROPE && blockIdx.x < 16) {
    __syncthreads();
    ushort* Pl = (ushort*)As;    // [128][128] bf16 = 32 KB
#pragma unroll
    for (int mi = 0; mi < 4; ++mi)
#pragma unroll
      for (int j = 0; j < 4; ++j) {
        int rl = wm + mi * 16 + lk * 4 + j;
#pragma unroll
        for (int ni = 0; ni < 4; ++ni)
          Pl[rl * 128 + wn + ni * 16 + lr] = f2bf(acc[mi][ni][j]);
      }
    __syncthreads();
    const bool lo = (wn == 0);
#pragma unroll
    for (int mi = 0; mi < 4; ++mi)
#pragma unroll
      for (int j = 0; j < 4; ++j) {
        int rl = wm + mi * 16 + lk * 4 + j;
        int row = bm + rl;
#pragma unroll
        for (int ni = 0; ni < 4; ++ni) {
          int d = wn + ni * 16 + lr;
          float a = bf2f(Pl[rl * 128 + d]);
          float b = bf2f(Pl[rl * 128 + (d ^ 64)]);
          float cs = cosb[row * 128 + d], sn = sinb[row * 128 + d];
          float v = lo ? (a * cs - b * sn) : (a * cs + b * sn);
          ((ushort*)C0)[(size_t)row * ldc + bn + d] = f2bf(v);
        }
      }
    return;
  }

#pragma unroll
  for (int mi = 0; mi < 4; ++mi)
#pragma unroll
    for (int j = 0; j < 4; ++j) {
      int row = bm + wm + mi * 16 + lk * 4 + j;
#pragma unroll
      for (int ni = 0; ni < 4; ++ni) {
        int col = bn + wn + ni * 16 + lr;
        if (OUT_BF16) ((ushort*)C0)[blockIdx.z * strC + (size_t)row * ldc + col] = f2bf(acc[mi][ni][j]);
        else          ((float*)C0)[blockIdx.z * strC + (size_t)row * ldc + col]  = acc[mi][ni][j];
      }
    }
}

// ---------------------------------------------------------------------------
// vkeys transpose: dstb (bf16) and dstf (f32), both [hv][n=2048][r=128]
// ---------------------------------------------------------------------------
__global__ __launch_bounds__(256) void transpose_cvt_vk(
    const float* __restrict__ src0, ushort* __restrict__ dstb,
    float* __restrict__ dstf)
{
  const float* src = src0 + (size_t)blockIdx.z * 262144;
  ushort* db = dstb + (size_t)blockIdx.z * 262144;
  float*  df = dstf + (size_t)blockIdx.z * 262144;
  __shared__ float tile[64][65];
  const int r0 = blockIdx.y << 6, c0 = blockIdx.x << 6;
  const int t = threadIdx.x;
  for (int i = t; i < 1024; i += 256) {
    int r = i >> 4, c = (i & 15) << 2;
    float4 v = *(const float4*)(src + (size_t)(r0 + r) * 2048 + c0 + c);
    tile[r][c] = v.x; tile[r][c+1] = v.y; tile[r][c+2] = v.z; tile[r][c+3] = v.w;
  }
  __syncthreads();
  int c = t >> 2, rb = (t & 3) << 4;
#pragma unroll
  for (int u = 0; u < 16; u += 4) {
    float4 f = make_float4(tile[rb+u+0][c], tile[rb+u+1][c],
                           tile[rb+u+2][c], tile[rb+u+3][c]);
    ushort4 o; o.x = f2bf(f.x); o.y = f2bf(f.y); o.z = f2bf(f.z); o.w = f2bf(f.w);
    *(ushort4*)(db + (size_t)(c0 + c) * 128 + r0 + rb + u) = o;
    *(float4*) (df + (size_t)(c0 + c) * 128 + r0 + rb + u) = f;
  }
}

// Wvq transpose -> hi/lo bf16, [512][2048] each. grid (8, 32).
__global__ __launch_bounds__(256) void transpose_cvt_hl(
    const float* __restrict__ src, ushort* __restrict__ dh,
    ushort* __restrict__ dl)
{
  __shared__ float tile[64][65];
  const int r0 = blockIdx.y << 6, c0 = blockIdx.x << 6;
  const int t = threadIdx.x;
  for (int i = t; i < 1024; i += 256) {
    int r = i >> 4, c = (i & 15) << 2;
    float4 v = *(const float4*)(src + (size_t)(r0 + r) * 512 + c0 + c);
    tile[r][c] = v.x; tile[r][c+1] = v.y; tile[r][c+2] = v.z; tile[r][c+3] = v.w;
  }
  __syncthreads();
  int c = t >> 2, rb = (t & 3) << 4;
#pragma unroll
  for (int u = 0; u < 16; u += 4) {
    ushort4 oh, ol;
#pragma unroll
    for (int q = 0; q < 4; ++q) {
      float x = tile[rb + u + q][c];
      ushort hi = f2bf(x);
      ushort lo = f2bf(x - bf2f(hi));
      ((ushort*)&oh)[q] = hi; ((ushort*)&ol)[q] = lo;
    }
    *(ushort4*)(dh + (size_t)(c0 + c) * 2048 + r0 + rb + u) = oh;
    *(ushort4*)(dl + (size_t)(c0 + c) * 2048 + r0 + rb + u) = ol;
  }
}

// triple-source weight transpose: z=0 Wq, z=1 Wk, z=2 Wo (2048x2048 each)
__global__ __launch_bounds__(256) void transpose_cvt_w3(
    const float* __restrict__ srcA, const float* __restrict__ srcB,
    const float* __restrict__ srcC, ushort* __restrict__ dst0)
{
  const float* src = (blockIdx.z == 0) ? srcA : (blockIdx.z == 1) ? srcB : srcC;
  ushort* dst = dst0 + (size_t)blockIdx.z * 4194304;
  __shared__ float tile[64][65];
  const int r0 = blockIdx.y << 6, c0 = blockIdx.x << 6;
  const int t = threadIdx.x;
  for (int i = t; i < 1024; i += 256) {
    int r = i >> 4, c = (i & 15) << 2;
    float4 v = *(const float4*)(src + (size_t)(r0 + r) * 2048 + c0 + c);
    tile[r][c] = v.x; tile[r][c+1] = v.y; tile[r][c+2] = v.z; tile[r][c+3] = v.w;
  }
  __syncthreads();
  int c = t >> 2, rb = (t & 3) << 4;
#pragma unroll
  for (int u = 0; u < 16; u += 4) {
    ushort4 o;
    o.x = f2bf(tile[rb+u+0][c]); o.y = f2bf(tile[rb+u+1][c]);
    o.z = f2bf(tile[rb+u+2][c]); o.w = f2bf(tile[rb+u+3][c]);
    *(ushort4*)(dst + (size_t)(c0 + c) * 2048 + r0 + rb + u) = o;
  }
}

// bf16 -> bf16 transpose (2048x2048)
__global__ __launch_bounds__(256) void transpose_bf(
    const ushort* __restrict__ src, ushort* __restrict__ dst)
{
  __shared__ ushort tile[64][66];
  const int r0 = blockIdx.y << 6, c0 = blockIdx.x << 6;
  const int t = threadIdx.x;
  for (int i = t; i < 512; i += 256) {
    int r = i >> 3, c8 = (i & 7) << 3;
    *(u16x8*)(&tile[r][c8]) = *(const u16x8*)(src + (size_t)(r0 + r) * 2048 + c0 + c8);
  }
  __syncthreads();
  for (int i = t; i < 512; i += 256) {
    int c = i >> 3, r8 = (i & 7) << 3;
    u16x8 o;
#pragma unroll
    for (int u = 0; u < 8; ++u) o[u] = tile[r8 + u][c];
    *(u16x8*)(dst + (size_t)(c0 + c) * 2048 + r0 + r8) = o;
  }
}

// vemb -> bf16; hs -> hi bf16 + lo bf16 (for vq emulation). 3M float4 total.
__global__ __launch_bounds__(256) void cvt3_bf16(const float* __restrict__ vemb,
    ushort* __restrict__ vemb_bf, const float* __restrict__ hs,
    ushort* __restrict__ hs_hi, ushort* __restrict__ hs_lo)
{
  int gid = blockIdx.x * 256 + threadIdx.x;
  if (gid < 1048576) {
    float4 v = ((const float4*)vemb)[gid];
    ushort4 o; o.x = f2bf(v.x); o.y = f2bf(v.y); o.z = f2bf(v.z); o.w = f2bf(v.w);
    ((ushort4*)vemb_bf)[gid] = o;
  } else {
    int i = gid - 1048576;
    float4 v = ((const float4*)hs)[i];
    ushort4 oh, ol;
    float xs[4] = {v.x, v.y, v.z, v.w};
#pragma unroll
    for (int q = 0; q < 4; ++q) {
      ushort hi = f2bf(xs[q]);
      ((ushort*)&oh)[q] = hi;
      ((ushort*)&ol)[q] = f2bf(xs[q] - bf2f(hi));
    }
    ((ushort4*)hs_hi)[i] = oh;
    ((ushort4*)hs_lo)[i] = ol;
  }
}

// ---------------------------------------------------------------------------
// Fused top-k: packed-u32 candidates (sortable-bf16 | 2047-idx), DPP merge,
// exact f32 recompute on contiguous transposed v_keys, exact top-4.
// ---------------------------------------------------------------------------
__global__ __launch_bounds__(256) void topk_sel(const ushort* __restrict__ sim,
    const float* __restrict__ vq, const float* __restrict__ vkTf,
    int* __restrict__ idxo)
{
  const int row = blockIdx.x * 4 + (threadIdx.x >> 6);
  const int hv = row >> 11, s = row & 2047;
  const int lane = threadIdx.x & 63;
  const ushort* r = sim + (size_t)row * 2048;

  unsigned v[8];
#pragma unroll
  for (int p = 0; p < 8; ++p) v[p] = 0u;
  for (int j = 0; j < 4; ++j) {
    int nb = (lane + (j << 6)) << 3;
    u16x8 e = *(const u16x8*)(r + nb);
#pragma unroll
    for (int u = 0; u < 8; ++u) {
      unsigned pk = (bf_sortable(e[u]) << 16) | (unsigned)(2047 - (nb + u));
      if (pk > v[7]) {
        v[7] = pk;
#pragma unroll
        for (int p = 7; p > 0; --p)
          if (v[p] > v[p-1]) { unsigned tt = v[p]; v[p] = v[p-1]; v[p-1] = tt; }
      }
    }
  }
  int out_n[8];
#pragma unroll
  for (int r8 = 0; r8 < 8; ++r8) {
    unsigned m = wave_umax64(v[0]);
    out_n[r8] = 2047 - (int)(m & 0x7FFu);
    if (v[0] == m) {
#pragma unroll
      for (int p = 0; p < 7; ++p) v[p] = v[p+1];
      v[7] = 0u;
    }
  }
  const int c = lane & 7, rc = lane >> 3;
  int n = 0;
#pragma unroll
  for (int p = 0; p < 8; ++p) if (p == c) n = out_n[p];
  const float* vqr = vq + (size_t)s * 512 + hv * 128 + rc * 16;
  const float* vkf = vkTf + (size_t)hv * 262144 + (size_t)n * 128 + rc * 16;
  float acc = 0.f;
#pragma unroll
  for (int u = 0; u < 16; ++u) acc = fmaf(vqr[u], vkf[u], acc);
  acc += __shfl_xor(acc, 8);
  acc += __shfl_xor(acc, 16);
  acc += __shfl_xor(acc, 32);
  float cv = acc; int ci = n;
  int picks[4];
#pragma unroll
  for (int p = 0; p < 4; ++p) {
    float bv = cv; int bi = ci;
#pragma unroll
    for (int d = 1; d < 8; d <<= 1) {
      float ov = __shfl_xor(bv, d); int oi = __shfl_xor(bi, d);
      if (ov > bv || (ov == bv && oi < bi)) { bv = ov; bi = oi; }
    }
    picks[p] = bi;
    if (bi == ci) cv = -FLT_MAX;
  }
  if (lane == 0) {
#pragma unroll
    for (int p = 0; p < 4; ++p) idxo[(size_t)row * 4 + p] = picks[p];
  }
}

// ---------------------------------------------------------------------------
__global__ __launch_bounds__(256) void gather_mul_bf(const float* __restrict__ hs,
    const ushort* __restrict__ vemb_bf, const int* __restrict__ idx,
    ushort* __restrict__ vb)
{
  const int s = blockIdx.x;
  const int t = threadIdx.x;
  __shared__ int id[16];
  if (t < 16) id[t] = idx[((size_t)(t >> 2) * 2048 + s) * 4 + (t & 3)];
  __syncthreads();
  int d0 = t << 3;
  float g[8] = {0.f, 0.f, 0.f, 0.f, 0.f, 0.f, 0.f, 0.f};
#pragma unroll
  for (int e = 0; e < 16; ++e) {
    u16x8 ve = *(const u16x8*)(vemb_bf + (size_t)id[e] * 2048 + d0);
#pragma unroll
    for (int u = 0; u < 8; ++u) g[u] += bf2f(ve[u]);
  }
  float4 h0 = *(const float4*)(hs + (size_t)s * 2048 + d0);
  float4 h1 = *(const float4*)(hs + (size_t)s * 2048 + d0 + 4);
  float hv[8] = {h0.x, h0.y, h0.z, h0.w, h1.x, h1.y, h1.z, h1.w};
  u16x8 o;
#pragma unroll
  for (int u = 0; u < 8; ++u) o[u] = f2bf(hv[u] * g[u]);
  *(u16x8*)(vb + (size_t)s * 2048 + d0) = o;
}

__global__ __launch_bounds__(256) void vmean_part(const ushort* __restrict__ vb,
                                                  float* __restrict__ part)
{
  const int h = blockIdx.y, chunk = blockIdx.x;
  const int t = threadIdx.x, d = t & 127, half = t >> 7;
  float s = 0.f;
  int r0 = chunk * 256 + half * 128;
  for (int r = r0; r < r0 + 128; ++r)
    s += bf2f(vb[(size_t)r * 2048 + h * 128 + d]);
  __shared__ float red[256];
  red[t] = s;
  __syncthreads();
  if (t < 128) part[(size_t)(h * 8 + chunk) * 128 + d] = red[t] + red[t + 128];
}

__global__ __launch_bounds__(256) void vmean_i0(const float* __restrict__ part,
    const float* __restrict__ amask, const float* __restrict__ dmask,
    float* __restrict__ vmean, int* __restrict__ i0)
{
  const int h = blockIdx.x, t = threadIdx.x;
  if (t < 128) {
    float s = 0.f;
#pragma unroll
    for (int c = 0; c < 8; ++c) s += part[(size_t)(h * 8 + c) * 128 + t];
    vmean[h * 128 + t] = s * (1.f / 2048.f);
  }
  int best = 0x7fffffff;
  for (int j = t; j < 2048; j += 256) {
    if (amask[j] * dmask[h * 2048 + j] != 0.f) { best = j; break; }
  }
  __shared__ int red[256];
  red[t] = best;
  __syncthreads();
  for (int off = 128; off > 0; off >>= 1) {
    if (t < off) red[t] = min(red[t], red[t + off]);
    __syncthreads();
  }
  if (t == 0) i0[h] = red[0];
}

// ---------------------------------------------------------------------------
// MFMA flash attention v2: per-stripe blocks (grid 512, LPT big-stripe-first,
// XCD-swizzled), KVBLK=32, 2 k-parity groups x 4 row waves, double-buffered
// K/V LDS, 77.8 KB -> 2 blocks/CU (4 waves/SIMD). exp2 softmax, defer-max,
// MFMA-l. Both parity groups run exactly stripe+1 tiles (balanced).
// ---------------------------------------------------------------------------
#define QLD 4096
__global__ __launch_bounds__(512, 4) void attn_mfma(
    const ushort* __restrict__ qb, const ushort* __restrict__ kb,
    const ushort* __restrict__ vt, const float* __restrict__ amask,
    const float* __restrict__ dmask, const float* __restrict__ vmean,
    const int* __restrict__ i0, ushort* __restrict__ ao)
{
  const int L = blockIdx.x;
  const int h = (L & 7) | (((L >> 3) & 1) << 3);   // head; L%8 == h%8 (XCD)
  const int stripe = 31 - (L >> 4);                // LPT: big stripes first
  const int q0 = stripe << 6;
  const int niter = stripe + 1;                    // per-parity 32-col tiles

  const int t = threadIdx.x, w = t >> 6, lane = t & 63;
  const int g = w >> 2, wg = w & 3;
  const int lr = lane & 15, lk = lane >> 4;

  // LDS 77824 B:
  //  [0,32K)   K tiles:  g*16384 + buf*8192 + [32 rows][256B], swz (row&7)<<4
  //  [32K,64K) V tiles:  g*16384 + buf*8192 + [128 d][64B],    swz (row&3)<<4
  //  [64K,72K) Ps:       g*4096  + [64 rows][64B],             swz (row&3)<<4
  //  [72K,76K) madd bf16[2048]
  //  merge: accL aliases [0,33792); smv/slv alias Ps (dead at merge)
  __shared__ char smem[77824];
  float*  accL   = (float*)smem;
  float*  smv    = (float*)(smem + 65536);
  float*  slv    = (float*)(smem + 66048);
  ushort* maddL  = (ushort*)(smem + 73728);
  char*   Kb0    = smem;
  char*   Vb0    = smem + 32768;
  char*   Pbase  = smem + 65536 + g * 4096;

  const int i0h = i0[h];

  bf16x8 onesb;
#pragma unroll
  for (int u = 0; u < 8; ++u) onesb[u] = (short)0x3F80;  // bf16 1.0

  for (int j = t; j < 2048; j += 512)
    maddL[j] = (amask[j] * dmask[h * 2048 + j] == 0.f) ? (ushort)0xFF80 /*-inf*/ : (ushort)0;

  // Q fragments in registers
  const int qrow = q0 + wg * 16 + lr;
  bf16x8 qf[4];
#pragma unroll
  for (int kk = 0; kk < 4; ++kk)
    qf[kk] = *(const bf16x8*)(qb + (size_t)qrow * QLD + h * 128 + kk * 32 + lk * 8);

  // prologue: stage tile g (c0 = g*32) into buf 0
  {
    const int c0p = g << 5;
#pragma unroll
    for (int qI = 0; qI < 2; ++qI) {
      int b = qI * 4096 + wg * 1024 + lane * 16;
      { int row = b >> 8, colb = b & 255;
        int src = colb ^ ((row & 7) << 4);
        gload_lds16((const char*)kb + ((size_t)(c0p + row) * QLD + h * 128) * 2 + src,
                    Kb0 + g * 16384 + b); }
      { int row = b >> 6, colb = b & 63;
        int src = colb ^ ((row & 3) << 4);
        gload_lds16((const char*)vt + ((size_t)(h * 128 + row) * 2048 + c0p) * 2 + src,
                    Vb0 + g * 16384 + b); }
    }
  }

  float m[4];
  f32x4 acc_l = (f32x4){0.f, 0.f, 0.f, 0.f};
  f32x4 acc_o[8];
#pragma unroll
  for (int j = 0; j < 4; ++j) m[j] = -FLT_MAX;
#pragma unroll
  for (int ni = 0; ni < 8; ++ni) acc_o[ni] = (f32x4){0.f, 0.f, 0.f, 0.f};

  int cur = 0;
  for (int it = 0; it < niter; ++it) {
    const int c0 = (2 * it + g) << 5;
    const bool diag = (c0 >= q0);
    __syncthreads();   // buf cur staged; prev readers done; maddL ready (it=0)

    // prefetch tile+2 (c0+64) into buf cur^1
    if (it + 1 < niter) {
      const int cn = c0 + 64;
      const int nb = cur ^ 1;
#pragma unroll
      for (int qI = 0; qI < 2; ++qI) {
        int b = qI * 4096 + wg * 1024 + lane * 16;
        { int row = b >> 8, colb = b & 255;
          int src = colb ^ ((row & 7) << 4);
          gload_lds16((const char*)kb + ((size_t)(cn + row) * QLD + h * 128) * 2 + src,
                      Kb0 + g * 16384 + nb * 8192 + b); }
        { int row = b >> 6, colb = b & 63;
          int src = colb ^ ((row & 3) << 4);
          gload_lds16((const char*)vt + ((size_t)(h * 128 + row) * 2048 + cn) * 2 + src,
                      Vb0 + g * 16384 + nb * 8192 + b); }
      }
    }

    float madd[2];
#pragma unroll
    for (int ni = 0; ni < 2; ++ni)
      madd[ni] = bf2f(maddL[c0 + ni * 16 + lr]);

    // ---- QK(t): 4 kk x 2 ni
    const char* Kbase = Kb0 + g * 16384 + cur * 8192;
    f32x4 sacc[2];
#pragma unroll
    for (int ni = 0; ni < 2; ++ni) sacc[ni] = (f32x4){0.f, 0.f, 0.f, 0.f};
    __builtin_amdgcn_s_setprio(1);
#pragma unroll
    for (int kk = 0; kk < 4; ++kk) {
#pragma unroll
      for (int ni = 0; ni < 2; ++ni) {
        int krow = ni * 16 + lr;
        bf16x8 bfr = *(const bf16x8*)(Kbase + krow * 256 + ((kk * 64 + lk * 16) ^ ((krow & 7) << 4)));
        sacc[ni] = __builtin_amdgcn_mfma_f32_16x16x32_bf16(qf[kk], bfr, sacc[ni], 0, 0, 0);
      }
    }
    __builtin_amdgcn_s_setprio(0);

    // ---- SM(t): defer-max; l from MFMA ones-column
#pragma unroll
    for (int j = 0; j < 4; ++j) {
      int grow = q0 + wg * 16 + lk * 4 + j;
      float x[2];
#pragma unroll
      for (int ni = 0; ni < 2; ++ni) {
        float v = fmaf(sacc[ni][j], SCALE_L2E, madd[ni]);
        if (diag && c0 + ni * 16 + lr > grow) v = NEG_MIN;
        x[ni] = v;
      }
      float pm = fmaxf(x[0], x[1]);
      if (!__all(pm <= m[j] + 16.f)) {
        float tmax = pm;
        tmax = fmaxf(tmax, dpp_ror<0x121>(tmax));
        tmax = fmaxf(tmax, dpp_ror<0x122>(tmax));
        tmax = fmaxf(tmax, dpp_ror<0x124>(tmax));
        tmax = fmaxf(tmax, dpp_ror<0x128>(tmax));
        float mn = fmaxf(m[j], tmax);
        if (mn > m[j]) {
          float sc = exp2f(m[j] - mn);
          acc_l[j] *= sc;
#pragma unroll
          for (int ni = 0; ni < 8; ++ni) acc_o[ni][j] *= sc;
          m[j] = mn;
        }
      }
      int prow = wg * 16 + lk * 4 + j;
#pragma unroll
      for (int ni = 0; ni < 2; ++ni) {
        float p = exp2f(x[ni] - m[j]);
        *(ushort*)(Pbase + prow * 64 + ((2 * (ni * 16 + lr)) ^ ((prow & 3) << 4))) = f2bf(p);
      }
    }

    // ---- PV(t): 1 k-slice of 32
    const char* Vbase = Vb0 + g * 16384 + cur * 8192;
    __builtin_amdgcn_s_setprio(1);
    {
      int prow = wg * 16 + lr;
      bf16x8 a = *(const bf16x8*)(Pbase + prow * 64 + ((lk * 16) ^ ((prow & 3) << 4)));
      acc_l = __builtin_amdgcn_mfma_f32_16x16x32_bf16(a, onesb, acc_l, 0, 0, 0);
#pragma unroll
      for (int ni = 0; ni < 8; ++ni) {
        int vrow = ni * 16 + lr;
        bf16x8 bfr = *(const bf16x8*)(Vbase + vrow * 64 + ((lk * 16) ^ ((vrow & 3) << 4)));
        acc_o[ni] = __builtin_amdgcn_mfma_f32_16x16x32_bf16(a, bfr, acc_o[ni], 0, 0, 0);
      }
    }
    __builtin_amdgcn_s_setprio(0);
    cur ^= 1;
  }

  // ---- merge the two k-parity partials, write output (group 0)
  __syncthreads();
  if (lr == 0) {
#pragma unroll
    for (int j = 0; j < 4; ++j) {
      int r = wg * 16 + lk * 4 + j;
      smv[g * 64 + r] = m[j];
      slv[g * 64 + r] = acc_l[j];
    }
  }
  __syncthreads();
  float myf[4], lcomb[4];
#pragma unroll
  for (int j = 0; j < 4; ++j) {
    int r = wg * 16 + lk * 4 + j;
    float m0 = smv[r], m1 = smv[64 + r];
    float l0 = slv[r], l1 = slv[64 + r];
    float mm = fmaxf(m0, m1);
    float f0 = exp2f(m0 - mm), f1 = exp2f(m1 - mm);
    lcomb[j] = l0 * f0 + l1 * f1;
    myf[j] = (g == 0) ? f0 : f1;
  }
  if (g == 1) {
#pragma unroll
    for (int j = 0; j < 4; ++j) {
      int r = wg * 16 + lk * 4 + j;
#pragma unroll
      for (int ni = 0; ni < 8; ++ni)
        accL[r * 132 + ni * 16 + lr] = acc_o[ni][j] * myf[j];
    }
  }
  __syncthreads();
  if (g == 0) {
#pragma unroll
    for (int j = 0; j < 4; ++j) {
      int row = q0 + wg * 16 + lk * 4 + j;
      int r = wg * 16 + lk * 4 + j;
      if (row < i0h) {
#pragma unroll
        for (int ni = 0; ni < 8; ++ni)
          ao[(size_t)row * 2048 + h * 128 + ni * 16 + lr] = f2bf(vmean[h * 128 + ni * 16 + lr]);
      } else {
        float inv = 1.f / lcomb[j];
#pragma unroll
        for (int ni = 0; ni < 8; ++ni) {
          float o = fmaf(acc_o[ni][j], myf[j], accL[r * 132 + ni * 16 + lr]);
          ao[(size_t)row * 2048 + h * 128 + ni * 16 + lr] = f2bf(o * inv);
        }
      }
    }
  }
}

// ---------------------------------------------------------------------------
extern "C" void kernel_launch(void* const* d_in, const int* in_sizes, int n_in,
                              void* d_out, int out_size, void* d_ws, size_t ws_size,
                              hipStream_t stream)
{
  const float* hs    = (const float*)d_in[0];
  const float* amask = (const float*)d_in[1];
  const float* cosb  = (const float*)d_in[2];
  const float* sinb  = (const float*)d_in[3];
  const float* dmask = (const float*)d_in[4];
  const float* Wq    = (const float*)d_in[5];
  const float* Wk    = (const float*)d_in[6];
  const float* Wvq   = (const float*)d_in[7];
  const float* vkeys = (const float*)d_in[8];
  const float* vemb  = (const float*)d_in[9];
  const float* Wo    = (const float*)d_in[10];
  float* outp = (float*)d_out;

  char* ws = (char*)d_ws;
  const size_t MB = 1048576;
  float*  pvq     = (float*) (ws + 0);              // A: [0,32) 8 partials
  ushort* WvqTh   = (ushort*)(ws + 32*MB);          // A: [32,34)
  ushort* WvqTl   = (ushort*)(ws + 34*MB);          // A: [34,36)
  ushort* hs_lo   = (ushort*)(ws + 55*MB);          // A: [55,63)
  float*  vq_f32  = (float*) (ws + 64*MB);          // A-B: [64,68)
  ushort* vq_bf   = (ushort*)(ws + 68*MB);          // A-B: [68,70)
  ushort* vkT     = (ushort*)(ws + 0);              // B: [0,2)   over dead pvq
  ushort* sim_bf  = (ushort*)(ws + 2*MB);           // B: [2,34)
  int*    idx     = (int*)   (ws + 34*MB);          // B-C: 128 KB
  float*  vkTf32  = (float*) (ws + 36*MB);          // B: [36,40)
  ushort* vemb_bf = (ushort*)(ws + 70*MB);          // A-C: [70,78)
  ushort* hs_bf   = (ushort*)(ws + 43*MB);          // A-D: [43,51)
  ushort* vb      = (ushort*)(ws + 0);              // C: [0,8)
  ushort* vt      = (ushort*)(ws + 8*MB);           // C-E: [8,16)
  float*  part    = (float*) (ws + 51*MB);          // C: 64 KB
  float*  vmean   = (float*) (ws + 51*MB + 65536);  // C-E: 8 KB
  int*    i0b     = (int*)   (ws + 51*MB + 73728);  // C-E: 64 B
  ushort* WBig    = (ushort*)(ws + 16*MB);          // D-E: [16,40) Wq|Wk|Wo^T
  ushort* WoT     = (ushort*)(ws + 32*MB);          // = WBig + 16MB
  ushort* qkC     = (ushort*)(ws + 52*MB);          // D-E: [52,68) q|k, ld 4096
  ushort* ao      = (ushort*)(ws + 0);              // E: [0,8)

  dim3 blk(256);
  // ---- prep: conversions + Wvq hi/lo transpose ----
  cvt3_bf16<<<dim3(8192), blk, 0, stream>>>(vemb, vemb_bf, hs, hs_bf, hs_lo);
  transpose_cvt_hl<<<dim3(8, 32), blk, 0, stream>>>(Wvq, WvqTh, WvqTl);
  // ---- routing path: vq via 3-term bf16 MFMA emulation ----
  gemm_vq3<<<dim3(4, 16, 8), blk, 0, stream>>>(hs_bf, hs_lo, 2048,
      WvqTh, WvqTl, 2048, pvq, 512, 256);
  reduce8_cvt<<<dim3(1024), blk, 0, stream>>>(pvq, vq_f32, vq_bf);
  transpose_cvt_vk<<<dim3(32, 2, 4), blk, 0, stream>>>(vkeys, vkT, vkTf32);
  gemm_bf16<1, 0><<<dim3(16, 16, 4), blk, 0, stream>>>(vq_bf, 512, vkT, 128,
      sim_bf, 2048, 128, 128, 262144, 4194304, nullptr, nullptr);
  topk_sel<<<dim3(2048), blk, 0, stream>>>(sim_bf, vq_f32, vkTf32, idx);
  // ---- v construction ----
  gather_mul_bf<<<dim3(2048), blk, 0, stream>>>(hs, vemb_bf, idx, vb);
  transpose_bf<<<dim3(32, 32), blk, 0, stream>>>(vb, vt);
  vmean_part<<<dim3(8, 16), blk, 0, stream>>>(vb, part);
  vmean_i0<<<dim3(16), blk, 0, stream>>>(part, amask, dmask, vmean, i0b);
  // ---- projections: Wq|Wk|Wo transpose (z=3), fused qk GEMM + RoPE ----
  transpose_cvt_w3<<<dim3(32, 32, 3), blk, 0, stream>>>(Wq, Wk, Wo, WBig);
  gemm_bf16<1, 1><<<dim3(32, 16, 1), blk, 0, stream>>>(hs_bf, 2048, WBig, 2048,
      qkC, 4096, 2048, 0, 0, 0, cosb, sinb);
  // ---- attention (grid 512: per-stripe LPT blocks, XCD-swizzled) ----
  attn_mfma<<<dim3(512), dim3(512), 0, stream>>>(qkC, qkC + 2048, vt, amask, dmask, vmean, i0b, ao);
  // ---- output projection ----
  gemm_bf16<0, 0><<<dim3(16, 16, 1), blk, 0, stream>>>(ao, 2048, WoT, 2048,
      outp, 2048, 2048, 0, 0, 0, nullptr, nullptr);
}

// Round 19
// 295.451 us; speedup vs baseline: 1.4730x; 1.4730x over previous
//
#include <hip/hip_runtime.h>
#include <float.h>

// B=1, S=2048, D=2048, H=16, HD=128, HV=4, R=128, NV=2048, K=4
#define NEG_MIN (-3.4028234663852886e38f)
#define INV_SQRT_HD 0.08838834764831845f
#define SCALE_L2E 0.12751791437968458f    // INV_SQRT_HD * log2(e)

typedef __attribute__((ext_vector_type(8))) short bf16x8;
typedef __attribute__((ext_vector_type(8))) unsigned short u16x8;
typedef __attribute__((ext_vector_type(4))) float f32x4;

__device__ __forceinline__ void gload_lds16(const void* g, void* l) {
  __builtin_amdgcn_global_load_lds((const __attribute__((address_space(1))) void*)g,
                                   (__attribute__((address_space(3))) void*)l, 16, 0, 0);
}
__device__ __forceinline__ ushort f2bf(float x) {
  union { float f; unsigned u; } v; v.f = x;
  unsigned r = v.u + 0x7fffu + ((v.u >> 16) & 1u);   // RNE
  return (ushort)(r >> 16);
}
__device__ __forceinline__ float bf2f(ushort u) {
  union { unsigned i; float f; } v; v.i = ((unsigned)u) << 16; return v.f;
}
template<int CTRL>
__device__ __forceinline__ float dpp_ror(float x) {
  return __int_as_float(__builtin_amdgcn_mov_dpp(__float_as_int(x), CTRL, 0xF, 0xF, true));
}
template<int CTRL>
__device__ __forceinline__ unsigned dpp_ror_u(unsigned x) {
  return (unsigned)__builtin_amdgcn_mov_dpp((int)x, CTRL, 0xF, 0xF, true);
}
__device__ __forceinline__ unsigned wave_umax64(unsigned x) {
  x = max(x, dpp_ror_u<0x121>(x));
  x = max(x, dpp_ror_u<0x122>(x));
  x = max(x, dpp_ror_u<0x124>(x));
  x = max(x, dpp_ror_u<0x128>(x));
  x = max(x, (unsigned)__shfl_xor((int)x, 16));
  x = max(x, (unsigned)__shfl_xor((int)x, 32));
  return x;
}
__device__ __forceinline__ unsigned bf_sortable(ushort b) {
  return (b & 0x8000u) ? (unsigned)(b ^ 0xFFFFu) : (unsigned)(b | 0x8000u);
}

// ---------------------------------------------------------------------------
// vq via 3-term bf16 emulation of f32 GEMM (MFMA pipe, rel err ~8e-6)
// ---------------------------------------------------------------------------
__global__ __launch_bounds__(256) void gemm_vq3(
    const ushort* __restrict__ Ah, const ushort* __restrict__ Al, int lda,
    const ushort* __restrict__ Bh, const ushort* __restrict__ Bl, int ldb,
    float* __restrict__ Cp, int ldc, int Kchunk)
{
  __shared__ ushort sAh[128 * 64], sAl[128 * 64];
  __shared__ ushort sBh[128 * 64], sBl[128 * 64];
  const int t = threadIdx.x, w = t >> 6, lane = t & 63;
  const int lr = lane & 15, lk = lane >> 4;
  const int bm = blockIdx.y << 7, bn = blockIdx.x << 7;
  const int k0base = blockIdx.z * Kchunk;
  const int wm = (w >> 1) << 6, wn = (w & 1) << 6;
  f32x4 acc[4][4];
#pragma unroll
  for (int i = 0; i < 4; ++i)
#pragma unroll
    for (int j = 0; j < 4; ++j) acc[i][j] = (f32x4){0.f, 0.f, 0.f, 0.f};

  for (int k0 = 0; k0 < Kchunk; k0 += 64) {
    const int kg = k0base + k0;
    __syncthreads();
#pragma unroll
    for (int qI = 0; qI < 4; ++qI) {
      int b = w * 4096 + qI * 1024 + lane * 16;
      int row = b >> 7, colb = b & 127;
      int src = colb ^ ((row & 7) << 4);
      gload_lds16((const char*)Ah + ((size_t)(bm + row) * lda + kg) * 2 + src,
                  (char*)sAh + w * 4096 + qI * 1024);
      gload_lds16((const char*)Al + ((size_t)(bm + row) * lda + kg) * 2 + src,
                  (char*)sAl + w * 4096 + qI * 1024);
      gload_lds16((const char*)Bh + ((size_t)(bn + row) * ldb + kg) * 2 + src,
                  (char*)sBh + w * 4096 + qI * 1024);
      gload_lds16((const char*)Bl + ((size_t)(bn + row) * ldb + kg) * 2 + src,
                  (char*)sBl + w * 4096 + qI * 1024);
    }
    __syncthreads();
#pragma unroll
    for (int kk = 0; kk < 2; ++kk) {
      bf16x8 ah[4], al[4], bh[4], bl[4];
#pragma unroll
      for (int mi = 0; mi < 4; ++mi) {
        int row = wm + mi * 16 + lr;
        int off = row * 128 + ((kk * 64 + lk * 16) ^ ((row & 7) << 4));
        ah[mi] = *(const bf16x8*)((const char*)sAh + off);
        al[mi] = *(const bf16x8*)((const char*)sAl + off);
      }
#pragma unroll
      for (int ni = 0; ni < 4; ++ni) {
        int row = wn + ni * 16 + lr;
        int off = row * 128 + ((kk * 64 + lk * 16) ^ ((row & 7) << 4));
        bh[ni] = *(const bf16x8*)((const char*)sBh + off);
        bl[ni] = *(const bf16x8*)((const char*)sBl + off);
      }
#pragma unroll
      for (int mi = 0; mi < 4; ++mi)
#pragma unroll
        for (int ni = 0; ni < 4; ++ni) {
          acc[mi][ni] = __builtin_amdgcn_mfma_f32_16x16x32_bf16(ah[mi], bh[ni], acc[mi][ni], 0, 0, 0);
          acc[mi][ni] = __builtin_amdgcn_mfma_f32_16x16x32_bf16(ah[mi], bl[ni], acc[mi][ni], 0, 0, 0);
          acc[mi][ni] = __builtin_amdgcn_mfma_f32_16x16x32_bf16(al[mi], bh[ni], acc[mi][ni], 0, 0, 0);
        }
    }
  }
  float* C = Cp + (size_t)blockIdx.z * 1048576;
#pragma unroll
  for (int mi = 0; mi < 4; ++mi)
#pragma unroll
    for (int j = 0; j < 4; ++j) {
      int row = bm + wm + mi * 16 + lk * 4 + j;
#pragma unroll
      for (int ni = 0; ni < 4; ++ni)
        C[(size_t)row * ldc + bn + wn + ni * 16 + lr] = acc[mi][ni][j];
    }
}

// deterministic 8-way reduce of split-K partials + bf16 copy (1M floats)
__global__ __launch_bounds__(256) void reduce8_cvt(const float* __restrict__ Cp,
    float* __restrict__ vq, ushort* __restrict__ vq_bf)
{
  int i = (blockIdx.x * 256 + threadIdx.x) << 2;
  float4 s = make_float4(0.f, 0.f, 0.f, 0.f);
#pragma unroll
  for (int z = 0; z < 8; ++z) {
    float4 a = *(const float4*)(Cp + (size_t)z * 1048576 + i);
    s.x += a.x; s.y += a.y; s.z += a.z; s.w += a.w;
  }
  *(float4*)(vq + i) = s;
  ushort4 o; o.x = f2bf(s.x); o.y = f2bf(s.y); o.z = f2bf(s.z); o.w = f2bf(s.w);
  *(ushort4*)(vq_bf + i) = o;
}

// ---------------------------------------------------------------------------
// bf16 MFMA GEMM (z-batched): C = A @ Bt^T. 128x128 tile, BK=64.
// 2-phase double-buffered LDS. ROPE=1: fused RoPE epilogue for bn<16.
// ---------------------------------------------------------------------------
template<int OUT_BF16, int ROPE>
__global__ __launch_bounds__(256) void gemm_bf16(
    const ushort* __restrict__ A0, int lda,
    const ushort* __restrict__ Bt0, int ldb,
    void* __restrict__ C0, int ldc, int Kd,
    size_t strA, size_t strB, size_t strC,
    const float* __restrict__ cosb, const float* __restrict__ sinb)
{
  const ushort* A  = A0  + blockIdx.z * strA;
  const ushort* Bt = Bt0 + blockIdx.z * strB;
  __shared__ ushort As[2][128 * 64];
  __shared__ ushort Bs[2][128 * 64];
  const int t = threadIdx.x, w = t >> 6, lane = t & 63;
  const int lr = lane & 15, lk = lane >> 4;
  const int bm = blockIdx.y << 7, bn = blockIdx.x << 7;
  const int wm = (w >> 1) << 6, wn = (w & 1) << 6;
  f32x4 acc[4][4];
#pragma unroll
  for (int i = 0; i < 4; ++i)
#pragma unroll
    for (int j = 0; j < 4; ++j) acc[i][j] = (f32x4){0.f, 0.f, 0.f, 0.f};

#define STAGE_QK(buf, kk0)                                                     \
  {                                                                            \
_Pragma("unroll")                                                              \
    for (int qI = 0; qI < 4; ++qI) {                                           \
      int b = w * 4096 + qI * 1024 + lane * 16;                                \
      int row = b >> 7, colb = b & 127;                                        \
      int src = colb ^ ((row & 7) << 4);                                       \
      gload_lds16((const char*)A + ((size_t)(bm + row) * lda + (kk0)) * 2 + src,\
                  (char*)As[buf] + w * 4096 + qI * 1024);                      \
      gload_lds16((const char*)Bt + ((size_t)(bn + row) * ldb + (kk0)) * 2 + src,\
                  (char*)Bs[buf] + w * 4096 + qI * 1024);                      \
    }                                                                          \
  }

  STAGE_QK(0, 0);
  int cur = 0;
  for (int k0 = 0; k0 < Kd; k0 += 64) {
    __syncthreads();
    if (k0 + 64 < Kd) STAGE_QK(cur ^ 1, k0 + 64);
#pragma unroll
    for (int kk = 0; kk < 2; ++kk) {
      bf16x8 af[4], bf[4];
#pragma unroll
      for (int mi = 0; mi < 4; ++mi) {
        int row = wm + mi * 16 + lr;
        af[mi] = *(const bf16x8*)((const char*)As[cur] + row * 128 + ((kk * 64 + lk * 16) ^ ((row & 7) << 4)));
      }
#pragma unroll
      for (int ni = 0; ni < 4; ++ni) {
        int row = wn + ni * 16 + lr;
        bf[ni] = *(const bf16x8*)((const char*)Bs[cur] + row * 128 + ((kk * 64 + lk * 16) ^ ((row & 7) << 4)));
      }
#pragma unroll
      for (int mi = 0; mi < 4; ++mi)
#pragma unroll
        for (int ni = 0; ni < 4; ++ni)
          acc[mi][ni] = __builtin_amdgcn_mfma_f32_16x16x32_bf16(af[mi], bf[ni], acc[mi][ni], 0, 0, 0);
    }
    cur ^= 1;
  }
#undef STAGE_QK

  if (ROPE && blockIdx.x < 16) {
    __syncthreads();
    ushort* Pl = (ushort*)As;    // [128][128] bf16 = 32 KB
#pragma unroll
    for (int mi = 0; mi < 4; ++mi)
#pragma unroll
      for (int j = 0; j < 4; ++j) {
        int rl = wm + mi * 16 + lk * 4 + j;
#pragma unroll
        for (int ni = 0; ni < 4; ++ni)
          Pl[rl * 128 + wn + ni * 16 + lr] = f2bf(acc[mi][ni][j]);
      }
    __syncthreads();
    const bool lo = (wn == 0);
#pragma unroll
    for (int mi = 0; mi < 4; ++mi)
#pragma unroll
      for (int j = 0; j < 4; ++j) {
        int rl = wm + mi * 16 + lk * 4 + j;
        int row = bm + rl;
#pragma unroll
        for (int ni = 0; ni < 4; ++ni) {
          int d = wn + ni * 16 + lr;
          float a = bf2f(Pl[rl * 128 + d]);
          float b = bf2f(Pl[rl * 128 + (d ^ 64)]);
          float cs = cosb[row * 128 + d], sn = sinb[row * 128 + d];
          float v = lo ? (a * cs - b * sn) : (a * cs + b * sn);
          ((ushort*)C0)[(size_t)row * ldc + bn + d] = f2bf(v);
        }
      }
    return;
  }

#pragma unroll
  for (int mi = 0; mi < 4; ++mi)
#pragma unroll
    for (int j = 0; j < 4; ++j) {
      int row = bm + wm + mi * 16 + lk * 4 + j;
#pragma unroll
      for (int ni = 0; ni < 4; ++ni) {
        int col = bn + wn + ni * 16 + lr;
        if (OUT_BF16) ((ushort*)C0)[blockIdx.z * strC + (size_t)row * ldc + col] = f2bf(acc[mi][ni][j]);
        else          ((float*)C0)[blockIdx.z * strC + (size_t)row * ldc + col]  = acc[mi][ni][j];
      }
    }
}

// ---------------------------------------------------------------------------
// vkeys transpose: dstb (bf16) and dstf (f32), both [hv][n=2048][r=128]
// ---------------------------------------------------------------------------
__global__ __launch_bounds__(256) void transpose_cvt_vk(
    const float* __restrict__ src0, ushort* __restrict__ dstb,
    float* __restrict__ dstf)
{
  const float* src = src0 + (size_t)blockIdx.z * 262144;
  ushort* db = dstb + (size_t)blockIdx.z * 262144;
  float*  df = dstf + (size_t)blockIdx.z * 262144;
  __shared__ float tile[64][65];
  const int r0 = blockIdx.y << 6, c0 = blockIdx.x << 6;
  const int t = threadIdx.x;
  for (int i = t; i < 1024; i += 256) {
    int r = i >> 4, c = (i & 15) << 2;
    float4 v = *(const float4*)(src + (size_t)(r0 + r) * 2048 + c0 + c);
    tile[r][c] = v.x; tile[r][c+1] = v.y; tile[r][c+2] = v.z; tile[r][c+3] = v.w;
  }
  __syncthreads();
  int c = t >> 2, rb = (t & 3) << 4;
#pragma unroll
  for (int u = 0; u < 16; u += 4) {
    float4 f = make_float4(tile[rb+u+0][c], tile[rb+u+1][c],
                           tile[rb+u+2][c], tile[rb+u+3][c]);
    ushort4 o; o.x = f2bf(f.x); o.y = f2bf(f.y); o.z = f2bf(f.z); o.w = f2bf(f.w);
    *(ushort4*)(db + (size_t)(c0 + c) * 128 + r0 + rb + u) = o;
    *(float4*) (df + (size_t)(c0 + c) * 128 + r0 + rb + u) = f;
  }
}

// Wvq transpose -> hi/lo bf16, [512][2048] each. grid (8, 32).
__global__ __launch_bounds__(256) void transpose_cvt_hl(
    const float* __restrict__ src, ushort* __restrict__ dh,
    ushort* __restrict__ dl)
{
  __shared__ float tile[64][65];
  const int r0 = blockIdx.y << 6, c0 = blockIdx.x << 6;
  const int t = threadIdx.x;
  for (int i = t; i < 1024; i += 256) {
    int r = i >> 4, c = (i & 15) << 2;
    float4 v = *(const float4*)(src + (size_t)(r0 + r) * 512 + c0 + c);
    tile[r][c] = v.x; tile[r][c+1] = v.y; tile[r][c+2] = v.z; tile[r][c+3] = v.w;
  }
  __syncthreads();
  int c = t >> 2, rb = (t & 3) << 4;
#pragma unroll
  for (int u = 0; u < 16; u += 4) {
    ushort4 oh, ol;
#pragma unroll
    for (int q = 0; q < 4; ++q) {
      float x = tile[rb + u + q][c];
      ushort hi = f2bf(x);
      ushort lo = f2bf(x - bf2f(hi));
      ((ushort*)&oh)[q] = hi; ((ushort*)&ol)[q] = lo;
    }
    *(ushort4*)(dh + (size_t)(c0 + c) * 2048 + r0 + rb + u) = oh;
    *(ushort4*)(dl + (size_t)(c0 + c) * 2048 + r0 + rb + u) = ol;
  }
}

// triple-source weight transpose: z=0 Wq, z=1 Wk, z=2 Wo (2048x2048 each)
__global__ __launch_bounds__(256) void transpose_cvt_w3(
    const float* __restrict__ srcA, const float* __restrict__ srcB,
    const float* __restrict__ srcC, ushort* __restrict__ dst0)
{
  const float* src = (blockIdx.z == 0) ? srcA : (blockIdx.z == 1) ? srcB : srcC;
  ushort* dst = dst0 + (size_t)blockIdx.z * 4194304;
  __shared__ float tile[64][65];
  const int r0 = blockIdx.y << 6, c0 = blockIdx.x << 6;
  const int t = threadIdx.x;
  for (int i = t; i < 1024; i += 256) {
    int r = i >> 4, c = (i & 15) << 2;
    float4 v = *(const float4*)(src + (size_t)(r0 + r) * 2048 + c0 + c);
    tile[r][c] = v.x; tile[r][c+1] = v.y; tile[r][c+2] = v.z; tile[r][c+3] = v.w;
  }
  __syncthreads();
  int c = t >> 2, rb = (t & 3) << 4;
#pragma unroll
  for (int u = 0; u < 16; u += 4) {
    ushort4 o;
    o.x = f2bf(tile[rb+u+0][c]); o.y = f2bf(tile[rb+u+1][c]);
    o.z = f2bf(tile[rb+u+2][c]); o.w = f2bf(tile[rb+u+3][c]);
    *(ushort4*)(dst + (size_t)(c0 + c) * 2048 + r0 + rb + u) = o;
  }
}

// bf16 -> bf16 transpose (2048x2048)
__global__ __launch_bounds__(256) void transpose_bf(
    const ushort* __restrict__ src, ushort* __restrict__ dst)
{
  __shared__ ushort tile[64][66];
  const int r0 = blockIdx.y << 6, c0 = blockIdx.x << 6;
  const int t = threadIdx.x;
  for (int i = t; i < 512; i += 256) {
    int r = i >> 3, c8 = (i & 7) << 3;
    *(u16x8*)(&tile[r][c8]) = *(const u16x8*)(src + (size_t)(r0 + r) * 2048 + c0 + c8);
  }
  __syncthreads();
  for (int i = t; i < 512; i += 256) {
    int c = i >> 3, r8 = (i & 7) << 3;
    u16x8 o;
#pragma unroll
    for (int u = 0; u < 8; ++u) o[u] = tile[r8 + u][c];
    *(u16x8*)(dst + (size_t)(c0 + c) * 2048 + r0 + r8) = o;
  }
}

// vemb -> bf16; hs -> hi bf16 + lo bf16 (for vq emulation). 3M float4 total.
__global__ __launch_bounds__(256) void cvt3_bf16(const float* __restrict__ vemb,
    ushort* __restrict__ vemb_bf, const float* __restrict__ hs,
    ushort* __restrict__ hs_hi, ushort* __restrict__ hs_lo)
{
  int gid = blockIdx.x * 256 + threadIdx.x;
  if (gid < 1048576) {
    float4 v = ((const float4*)vemb)[gid];
    ushort4 o; o.x = f2bf(v.x); o.y = f2bf(v.y); o.z = f2bf(v.z); o.w = f2bf(v.w);
    ((ushort4*)vemb_bf)[gid] = o;
  } else {
    int i = gid - 1048576;
    float4 v = ((const float4*)hs)[i];
    ushort4 oh, ol;
    float xs[4] = {v.x, v.y, v.z, v.w};
#pragma unroll
    for (int q = 0; q < 4; ++q) {
      ushort hi = f2bf(xs[q]);
      ((ushort*)&oh)[q] = hi;
      ((ushort*)&ol)[q] = f2bf(xs[q] - bf2f(hi));
    }
    ((ushort4*)hs_hi)[i] = oh;
    ((ushort4*)hs_lo)[i] = ol;
  }
}

// ---------------------------------------------------------------------------
// Fused top-k: packed-u32 candidates (sortable-bf16 | 2047-idx), DPP merge,
// exact f32 recompute on contiguous transposed v_keys, exact top-4.
// ---------------------------------------------------------------------------
__global__ __launch_bounds__(256) void topk_sel(const ushort* __restrict__ sim,
    const float* __restrict__ vq, const float* __restrict__ vkTf,
    int* __restrict__ idxo)
{
  const int row = blockIdx.x * 4 + (threadIdx.x >> 6);
  const int hv = row >> 11, s = row & 2047;
  const int lane = threadIdx.x & 63;
  const ushort* r = sim + (size_t)row * 2048;

  unsigned v[8];
#pragma unroll
  for (int p = 0; p < 8; ++p) v[p] = 0u;
  for (int j = 0; j < 4; ++j) {
    int nb = (lane + (j << 6)) << 3;
    u16x8 e = *(const u16x8*)(r + nb);
#pragma unroll
    for (int u = 0; u < 8; ++u) {
      unsigned pk = (bf_sortable(e[u]) << 16) | (unsigned)(2047 - (nb + u));
      if (pk > v[7]) {
        v[7] = pk;
#pragma unroll
        for (int p = 7; p > 0; --p)
          if (v[p] > v[p-1]) { unsigned tt = v[p]; v[p] = v[p-1]; v[p-1] = tt; }
      }
    }
  }
  int out_n[8];
#pragma unroll
  for (int r8 = 0; r8 < 8; ++r8) {
    unsigned m = wave_umax64(v[0]);
    out_n[r8] = 2047 - (int)(m & 0x7FFu);
    if (v[0] == m) {
#pragma unroll
      for (int p = 0; p < 7; ++p) v[p] = v[p+1];
      v[7] = 0u;
    }
  }
  const int c = lane & 7, rc = lane >> 3;
  int n = 0;
#pragma unroll
  for (int p = 0; p < 8; ++p) if (p == c) n = out_n[p];
  const float* vqr = vq + (size_t)s * 512 + hv * 128 + rc * 16;
  const float* vkf = vkTf + (size_t)hv * 262144 + (size_t)n * 128 + rc * 16;
  float acc = 0.f;
#pragma unroll
  for (int u = 0; u < 16; ++u) acc = fmaf(vqr[u], vkf[u], acc);
  acc += __shfl_xor(acc, 8);
  acc += __shfl_xor(acc, 16);
  acc += __shfl_xor(acc, 32);
  float cv = acc; int ci = n;
  int picks[4];
#pragma unroll
  for (int p = 0; p < 4; ++p) {
    float bv = cv; int bi = ci;
#pragma unroll
    for (int d = 1; d < 8; d <<= 1) {
      float ov = __shfl_xor(bv, d); int oi = __shfl_xor(bi, d);
      if (ov > bv || (ov == bv && oi < bi)) { bv = ov; bi = oi; }
    }
    picks[p] = bi;
    if (bi == ci) cv = -FLT_MAX;
  }
  if (lane == 0) {
#pragma unroll
    for (int p = 0; p < 4; ++p) idxo[(size_t)row * 4 + p] = picks[p];
  }
}

// ---------------------------------------------------------------------------
__global__ __launch_bounds__(256) void gather_mul_bf(const float* __restrict__ hs,
    const ushort* __restrict__ vemb_bf, const int* __restrict__ idx,
    ushort* __restrict__ vb)
{
  const int s = blockIdx.x;
  const int t = threadIdx.x;
  __shared__ int id[16];
  if (t < 16) id[t] = idx[((size_t)(t >> 2) * 2048 + s) * 4 + (t & 3)];
  __syncthreads();
  int d0 = t << 3;
  float g[8] = {0.f, 0.f, 0.f, 0.f, 0.f, 0.f, 0.f, 0.f};
#pragma unroll
  for (int e = 0; e < 16; ++e) {
    u16x8 ve = *(const u16x8*)(vemb_bf + (size_t)id[e] * 2048 + d0);
#pragma unroll
    for (int u = 0; u < 8; ++u) g[u] += bf2f(ve[u]);
  }
  float4 h0 = *(const float4*)(hs + (size_t)s * 2048 + d0);
  float4 h1 = *(const float4*)(hs + (size_t)s * 2048 + d0 + 4);
  float hv[8] = {h0.x, h0.y, h0.z, h0.w, h1.x, h1.y, h1.z, h1.w};
  u16x8 o;
#pragma unroll
  for (int u = 0; u < 8; ++u) o[u] = f2bf(hv[u] * g[u]);
  *(u16x8*)(vb + (size_t)s * 2048 + d0) = o;
}

__global__ __launch_bounds__(256) void vmean_part(const ushort* __restrict__ vb,
                                                  float* __restrict__ part)
{
  const int h = blockIdx.y, chunk = blockIdx.x;
  const int t = threadIdx.x, d = t & 127, half = t >> 7;
  float s = 0.f;
  int r0 = chunk * 256 + half * 128;
  for (int r = r0; r < r0 + 128; ++r)
    s += bf2f(vb[(size_t)r * 2048 + h * 128 + d]);
  __shared__ float red[256];
  red[t] = s;
  __syncthreads();
  if (t < 128) part[(size_t)(h * 8 + chunk) * 128 + d] = red[t] + red[t + 128];
}

__global__ __launch_bounds__(256) void vmean_i0(const float* __restrict__ part,
    const float* __restrict__ amask, const float* __restrict__ dmask,
    float* __restrict__ vmean, int* __restrict__ i0)
{
  const int h = blockIdx.x, t = threadIdx.x;
  if (t < 128) {
    float s = 0.f;
#pragma unroll
    for (int c = 0; c < 8; ++c) s += part[(size_t)(h * 8 + c) * 128 + t];
    vmean[h * 128 + t] = s * (1.f / 2048.f);
  }
  int best = 0x7fffffff;
  for (int j = t; j < 2048; j += 256) {
    if (amask[j] * dmask[h * 2048 + j] != 0.f) { best = j; break; }
  }
  __shared__ int red[256];
  red[t] = best;
  __syncthreads();
  for (int off = 128; off > 0; off >>= 1) {
    if (t < off) red[t] = min(red[t], red[t + off]);
    __syncthreads();
  }
  if (t == 0) i0[h] = red[0];
}

// ---------------------------------------------------------------------------
// MFMA flash attention v2: per-stripe blocks (grid 512, LPT big-stripe-first,
// XCD-swizzled), KVBLK=32, 2 k-parity groups x 4 row waves, double-buffered
// K/V LDS, 77.8 KB. Plain launch_bounds (R18's ",4" forced 64 VGPR -> spills).
// ---------------------------------------------------------------------------
#define QLD 4096
__global__ __launch_bounds__(512) void attn_mfma(
    const ushort* __restrict__ qb, const ushort* __restrict__ kb,
    const ushort* __restrict__ vt, const float* __restrict__ amask,
    const float* __restrict__ dmask, const float* __restrict__ vmean,
    const int* __restrict__ i0, ushort* __restrict__ ao)
{
  const int L = blockIdx.x;
  const int h = (L & 7) | (((L >> 3) & 1) << 3);   // head; L%8 == h%8 (XCD)
  const int stripe = 31 - (L >> 4);                // LPT: big stripes first
  const int q0 = stripe << 6;
  const int niter = stripe + 1;                    // per-parity 32-col tiles

  const int t = threadIdx.x, w = t >> 6, lane = t & 63;
  const int g = w >> 2, wg = w & 3;
  const int lr = lane & 15, lk = lane >> 4;

  __shared__ char smem[77824];
  float*  accL   = (float*)smem;
  float*  smv    = (float*)(smem + 65536);
  float*  slv    = (float*)(smem + 66048);
  ushort* maddL  = (ushort*)(smem + 73728);
  char*   Kb0    = smem;
  char*   Vb0    = smem + 32768;
  char*   Pbase  = smem + 65536 + g * 4096;

  const int i0h = i0[h];

  bf16x8 onesb;
#pragma unroll
  for (int u = 0; u < 8; ++u) onesb[u] = (short)0x3F80;  // bf16 1.0

  for (int j = t; j < 2048; j += 512)
    maddL[j] = (amask[j] * dmask[h * 2048 + j] == 0.f) ? (ushort)0xFF80 /*-inf*/ : (ushort)0;

  // Q fragments in registers
  const int qrow = q0 + wg * 16 + lr;
  bf16x8 qf[4];
#pragma unroll
  for (int kk = 0; kk < 4; ++kk)
    qf[kk] = *(const bf16x8*)(qb + (size_t)qrow * QLD + h * 128 + kk * 32 + lk * 8);

  // prologue: stage tile g (c0 = g*32) into buf 0
  {
    const int c0p = g << 5;
#pragma unroll
    for (int qI = 0; qI < 2; ++qI) {
      int b = qI * 4096 + wg * 1024 + lane * 16;
      { int row = b >> 8, colb = b & 255;
        int src = colb ^ ((row & 7) << 4);
        gload_lds16((const char*)kb + ((size_t)(c0p + row) * QLD + h * 128) * 2 + src,
                    Kb0 + g * 16384 + b); }
      { int row = b >> 6, colb = b & 63;
        int src = colb ^ ((row & 3) << 4);
        gload_lds16((const char*)vt + ((size_t)(h * 128 + row) * 2048 + c0p) * 2 + src,
                    Vb0 + g * 16384 + b); }
    }
  }

  float m[4];
  f32x4 acc_l = (f32x4){0.f, 0.f, 0.f, 0.f};
  f32x4 acc_o[8];
#pragma unroll
  for (int j = 0; j < 4; ++j) m[j] = -FLT_MAX;
#pragma unroll
  for (int ni = 0; ni < 8; ++ni) acc_o[ni] = (f32x4){0.f, 0.f, 0.f, 0.f};

  int cur = 0;
  for (int it = 0; it < niter; ++it) {
    const int c0 = (2 * it + g) << 5;
    const bool diag = (c0 >= q0);
    __syncthreads();   // buf cur staged; prev readers done; maddL ready (it=0)

    // prefetch tile+2 (c0+64) into buf cur^1
    if (it + 1 < niter) {
      const int cn = c0 + 64;
      const int nb = cur ^ 1;
#pragma unroll
      for (int qI = 0; qI < 2; ++qI) {
        int b = qI * 4096 + wg * 1024 + lane * 16;
        { int row = b >> 8, colb = b & 255;
          int src = colb ^ ((row & 7) << 4);
          gload_lds16((const char*)kb + ((size_t)(cn + row) * QLD + h * 128) * 2 + src,
                      Kb0 + g * 16384 + nb * 8192 + b); }
        { int row = b >> 6, colb = b & 63;
          int src = colb ^ ((row & 3) << 4);
          gload_lds16((const char*)vt + ((size_t)(h * 128 + row) * 2048 + cn) * 2 + src,
                      Vb0 + g * 16384 + nb * 8192 + b); }
      }
    }

    float madd[2];
#pragma unroll
    for (int ni = 0; ni < 2; ++ni)
      madd[ni] = bf2f(maddL[c0 + ni * 16 + lr]);

    // ---- QK(t): 4 kk x 2 ni
    const char* Kbase = Kb0 + g * 16384 + cur * 8192;
    f32x4 sacc[2];
#pragma unroll
    for (int ni = 0; ni < 2; ++ni) sacc[ni] = (f32x4){0.f, 0.f, 0.f, 0.f};
    __builtin_amdgcn_s_setprio(1);
#pragma unroll
    for (int kk = 0; kk < 4; ++kk) {
#pragma unroll
      for (int ni = 0; ni < 2; ++ni) {
        int krow = ni * 16 + lr;
        bf16x8 bfr = *(const bf16x8*)(Kbase + krow * 256 + ((kk * 64 + lk * 16) ^ ((krow & 7) << 4)));
        sacc[ni] = __builtin_amdgcn_mfma_f32_16x16x32_bf16(qf[kk], bfr, sacc[ni], 0, 0, 0);
      }
    }
    __builtin_amdgcn_s_setprio(0);

    // ---- SM(t): defer-max; l from MFMA ones-column
#pragma unroll
    for (int j = 0; j < 4; ++j) {
      int grow = q0 + wg * 16 + lk * 4 + j;
      float x[2];
#pragma unroll
      for (int ni = 0; ni < 2; ++ni) {
        float v = fmaf(sacc[ni][j], SCALE_L2E, madd[ni]);
        if (diag && c0 + ni * 16 + lr > grow) v = NEG_MIN;
        x[ni] = v;
      }
      float pm = fmaxf(x[0], x[1]);
      if (!__all(pm <= m[j] + 16.f)) {
        float tmax = pm;
        tmax = fmaxf(tmax, dpp_ror<0x121>(tmax));
        tmax = fmaxf(tmax, dpp_ror<0x122>(tmax));
        tmax = fmaxf(tmax, dpp_ror<0x124>(tmax));
        tmax = fmaxf(tmax, dpp_ror<0x128>(tmax));
        float mn = fmaxf(m[j], tmax);
        if (mn > m[j]) {
          float sc = exp2f(m[j] - mn);
          acc_l[j] *= sc;
#pragma unroll
          for (int ni = 0; ni < 8; ++ni) acc_o[ni][j] *= sc;
          m[j] = mn;
        }
      }
      int prow = wg * 16 + lk * 4 + j;
#pragma unroll
      for (int ni = 0; ni < 2; ++ni) {
        float p = exp2f(x[ni] - m[j]);
        *(ushort*)(Pbase + prow * 64 + ((2 * (ni * 16 + lr)) ^ ((prow & 3) << 4))) = f2bf(p);
      }
    }

    // ---- PV(t): 1 k-slice of 32
    const char* Vbase = Vb0 + g * 16384 + cur * 8192;
    __builtin_amdgcn_s_setprio(1);
    {
      int prow = wg * 16 + lr;
      bf16x8 a = *(const bf16x8*)(Pbase + prow * 64 + ((lk * 16) ^ ((prow & 3) << 4)));
      acc_l = __builtin_amdgcn_mfma_f32_16x16x32_bf16(a, onesb, acc_l, 0, 0, 0);
#pragma unroll
      for (int ni = 0; ni < 8; ++ni) {
        int vrow = ni * 16 + lr;
        bf16x8 bfr = *(const bf16x8*)(Vbase + vrow * 64 + ((lk * 16) ^ ((vrow & 3) << 4)));
        acc_o[ni] = __builtin_amdgcn_mfma_f32_16x16x32_bf16(a, bfr, acc_o[ni], 0, 0, 0);
      }
    }
    __builtin_amdgcn_s_setprio(0);
    cur ^= 1;
  }

  // ---- merge the two k-parity partials, write output (group 0)
  __syncthreads();
  if (lr == 0) {
#pragma unroll
    for (int j = 0; j < 4; ++j) {
      int r = wg * 16 + lk * 4 + j;
      smv[g * 64 + r] = m[j];
      slv[g * 64 + r] = acc_l[j];
    }
  }
  __syncthreads();
  float myf[4], lcomb[4];
#pragma unroll
  for (int j = 0; j < 4; ++j) {
    int r = wg * 16 + lk * 4 + j;
    float m0 = smv[r], m1 = smv[64 + r];
    float l0 = slv[r], l1 = slv[64 + r];
    float mm = fmaxf(m0, m1);
    float f0 = exp2f(m0 - mm), f1 = exp2f(m1 - mm);
    lcomb[j] = l0 * f0 + l1 * f1;
    myf[j] = (g == 0) ? f0 : f1;
  }
  if (g == 1) {
#pragma unroll
    for (int j = 0; j < 4; ++j) {
      int r = wg * 16 + lk * 4 + j;
#pragma unroll
      for (int ni = 0; ni < 8; ++ni)
        accL[r * 132 + ni * 16 + lr] = acc_o[ni][j] * myf[j];
    }
  }
  __syncthreads();
  if (g == 0) {
#pragma unroll
    for (int j = 0; j < 4; ++j) {
      int row = q0 + wg * 16 + lk * 4 + j;
      int r = wg * 16 + lk * 4 + j;
      if (row < i0h) {
#pragma unroll
        for (int ni = 0; ni < 8; ++ni)
          ao[(size_t)row * 2048 + h * 128 + ni * 16 + lr] = f2bf(vmean[h * 128 + ni * 16 + lr]);
      } else {
        float inv = 1.f / lcomb[j];
#pragma unroll
        for (int ni = 0; ni < 8; ++ni) {
          float o = fmaf(acc_o[ni][j], myf[j], accL[r * 132 + ni * 16 + lr]);
          ao[(size_t)row * 2048 + h * 128 + ni * 16 + lr] = f2bf(o * inv);
        }
      }
    }
  }
}

// ---------------------------------------------------------------------------
extern "C" void kernel_launch(void* const* d_in, const int* in_sizes, int n_in,
                              void* d_out, int out_size, void* d_ws, size_t ws_size,
                              hipStream_t stream)
{
  const float* hs    = (const float*)d_in[0];
  const float* amask = (const float*)d_in[1];
  const float* cosb  = (const float*)d_in[2];
  const float* sinb  = (const float*)d_in[3];
  const float* dmask = (const float*)d_in[4];
  const float* Wq    = (const float*)d_in[5];
  const float* Wk    = (const float*)d_in[6];
  const float* Wvq   = (const float*)d_in[7];
  const float* vkeys = (const float*)d_in[8];
  const float* vemb  = (const float*)d_in[9];
  const float* Wo    = (const float*)d_in[10];
  float* outp = (float*)d_out;

  char* ws = (char*)d_ws;
  const size_t MB = 1048576;
  float*  pvq     = (float*) (ws + 0);              // A: [0,32) 8 partials
  ushort* WvqTh   = (ushort*)(ws + 32*MB);          // A: [32,34)
  ushort* WvqTl   = (ushort*)(ws + 34*MB);          // A: [34,36)
  ushort* hs_lo   = (ushort*)(ws + 55*MB);          // A: [55,63)
  float*  vq_f32  = (float*) (ws + 64*MB);          // A-B: [64,68)
  ushort* vq_bf   = (ushort*)(ws + 68*MB);          // A-B: [68,70)
  ushort* vkT     = (ushort*)(ws + 0);              // B: [0,2)   over dead pvq
  ushort* sim_bf  = (ushort*)(ws + 2*MB);           // B: [2,34)
  int*    idx     = (int*)   (ws + 34*MB);          // B-C: 128 KB
  float*  vkTf32  = (float*) (ws + 36*MB);          // B: [36,40)
  ushort* vemb_bf = (ushort*)(ws + 70*MB);          // A-C: [70,78)
  ushort* hs_bf   = (ushort*)(ws + 43*MB);          // A-D: [43,51)
  ushort* vb      = (ushort*)(ws + 0);              // C: [0,8)
  ushort* vt      = (ushort*)(ws + 8*MB);           // C-E: [8,16)
  float*  part    = (float*) (ws + 51*MB);          // C: 64 KB
  float*  vmean   = (float*) (ws + 51*MB + 65536);  // C-E: 8 KB
  int*    i0b     = (int*)   (ws + 51*MB + 73728);  // C-E: 64 B
  ushort* WBig    = (ushort*)(ws + 16*MB);          // D-E: [16,40) Wq|Wk|Wo^T
  ushort* WoT     = (ushort*)(ws + 32*MB);          // = WBig + 16MB
  ushort* qkC     = (ushort*)(ws + 52*MB);          // D-E: [52,68) q|k, ld 4096
  ushort* ao      = (ushort*)(ws + 0);              // E: [0,8)

  dim3 blk(256);
  // ---- prep: conversions + Wvq hi/lo transpose ----
  cvt3_bf16<<<dim3(8192), blk, 0, stream>>>(vemb, vemb_bf, hs, hs_bf, hs_lo);
  transpose_cvt_hl<<<dim3(8, 32), blk, 0, stream>>>(Wvq, WvqTh, WvqTl);
  // ---- routing path: vq via 3-term bf16 MFMA emulation ----
  gemm_vq3<<<dim3(4, 16, 8), blk, 0, stream>>>(hs_bf, hs_lo, 2048,
      WvqTh, WvqTl, 2048, pvq, 512, 256);
  reduce8_cvt<<<dim3(1024), blk, 0, stream>>>(pvq, vq_f32, vq_bf);
  transpose_cvt_vk<<<dim3(32, 2, 4), blk, 0, stream>>>(vkeys, vkT, vkTf32);
  gemm_bf16<1, 0><<<dim3(16, 16, 4), blk, 0, stream>>>(vq_bf, 512, vkT, 128,
      sim_bf, 2048, 128, 128, 262144, 4194304, nullptr, nullptr);
  topk_sel<<<dim3(2048), blk, 0, stream>>>(sim_bf, vq_f32, vkTf32, idx);
  // ---- v construction ----
  gather_mul_bf<<<dim3(2048), blk, 0, stream>>>(hs, vemb_bf, idx, vb);
  transpose_bf<<<dim3(32, 32), blk, 0, stream>>>(vb, vt);
  vmean_part<<<dim3(8, 16), blk, 0, stream>>>(vb, part);
  vmean_i0<<<dim3(16), blk, 0, stream>>>(part, amask, dmask, vmean, i0b);
  // ---- projections: Wq|Wk|Wo transpose (z=3), fused qk GEMM + RoPE ----
  transpose_cvt_w3<<<dim3(32, 32, 3), blk, 0, stream>>>(Wq, Wk, Wo, WBig);
  gemm_bf16<1, 1><<<dim3(32, 16, 1), blk, 0, stream>>>(hs_bf, 2048, WBig, 2048,
      qkC, 4096, 2048, 0, 0, 0, cosb, sinb);
  // ---- attention (grid 512: per-stripe LPT blocks, XCD-swizzled) ----
  attn_mfma<<<dim3(512), dim3(512), 0, stream>>>(qkC, qkC + 2048, vt, amask, dmask, vmean, i0b, ao);
  // ---- output projection ----
  gemm_bf16<0, 0><<<dim3(16, 16, 1), blk, 0, stream>>>(ao, 2048, WoT, 2048,
      outp, 2048, 2048, 0, 0, 0, nullptr, nullptr);
}

// Round 20
// 289.607 us; speedup vs baseline: 1.5027x; 1.0202x over previous
//
#include <hip/hip_runtime.h>
#include <float.h>

// B=1, S=2048, D=2048, H=16, HD=128, HV=4, R=128, NV=2048, K=4
#define NEG_MIN (-3.4028234663852886e38f)
#define INV_SQRT_HD 0.08838834764831845f
#define SCALE_L2E 0.12751791437968458f    // INV_SQRT_HD * log2(e)

typedef __attribute__((ext_vector_type(8))) short bf16x8;
typedef __attribute__((ext_vector_type(8))) unsigned short u16x8;
typedef __attribute__((ext_vector_type(4))) float f32x4;

__device__ __forceinline__ void gload_lds16(const void* g, void* l) {
  __builtin_amdgcn_global_load_lds((const __attribute__((address_space(1))) void*)g,
                                   (__attribute__((address_space(3))) void*)l, 16, 0, 0);
}
__device__ __forceinline__ ushort f2bf(float x) {
  union { float f; unsigned u; } v; v.f = x;
  unsigned r = v.u + 0x7fffu + ((v.u >> 16) & 1u);   // RNE
  return (ushort)(r >> 16);
}
__device__ __forceinline__ float bf2f(ushort u) {
  union { unsigned i; float f; } v; v.i = ((unsigned)u) << 16; return v.f;
}
template<int CTRL>
__device__ __forceinline__ float dpp_ror(float x) {
  return __int_as_float(__builtin_amdgcn_mov_dpp(__float_as_int(x), CTRL, 0xF, 0xF, true));
}
template<int CTRL>
__device__ __forceinline__ unsigned dpp_ror_u(unsigned x) {
  return (unsigned)__builtin_amdgcn_mov_dpp((int)x, CTRL, 0xF, 0xF, true);
}
__device__ __forceinline__ unsigned wave_umax64(unsigned x) {
  x = max(x, dpp_ror_u<0x121>(x));
  x = max(x, dpp_ror_u<0x122>(x));
  x = max(x, dpp_ror_u<0x124>(x));
  x = max(x, (unsigned)__shfl_xor((int)x, 16));
  x = max(x, (unsigned)__shfl_xor((int)x, 32));
  return max(x, dpp_ror_u<0x128>(x));
}
__device__ __forceinline__ unsigned bf_sortable(ushort b) {
  return (b & 0x8000u) ? (unsigned)(b ^ 0xFFFFu) : (unsigned)(b | 0x8000u);
}

// ---------------------------------------------------------------------------
// vq via 3-term bf16 emulation of f32 GEMM (MFMA pipe, rel err ~8e-6)
// ---------------------------------------------------------------------------
__global__ __launch_bounds__(256) void gemm_vq3(
    const ushort* __restrict__ Ah, const ushort* __restrict__ Al, int lda,
    const ushort* __restrict__ Bh, const ushort* __restrict__ Bl, int ldb,
    float* __restrict__ Cp, int ldc, int Kchunk)
{
  __shared__ ushort sAh[128 * 64], sAl[128 * 64];
  __shared__ ushort sBh[128 * 64], sBl[128 * 64];
  const int t = threadIdx.x, w = t >> 6, lane = t & 63;
  const int lr = lane & 15, lk = lane >> 4;
  const int bm = blockIdx.y << 7, bn = blockIdx.x << 7;
  const int k0base = blockIdx.z * Kchunk;
  const int wm = (w >> 1) << 6, wn = (w & 1) << 6;
  f32x4 acc[4][4];
#pragma unroll
  for (int i = 0; i < 4; ++i)
#pragma unroll
    for (int j = 0; j < 4; ++j) acc[i][j] = (f32x4){0.f, 0.f, 0.f, 0.f};

  for (int k0 = 0; k0 < Kchunk; k0 += 64) {
    const int kg = k0base + k0;
    __syncthreads();
#pragma unroll
    for (int qI = 0; qI < 4; ++qI) {
      int b = w * 4096 + qI * 1024 + lane * 16;
      int row = b >> 7, colb = b & 127;
      int src = colb ^ ((row & 7) << 4);
      gload_lds16((const char*)Ah + ((size_t)(bm + row) * lda + kg) * 2 + src,
                  (char*)sAh + w * 4096 + qI * 1024);
      gload_lds16((const char*)Al + ((size_t)(bm + row) * lda + kg) * 2 + src,
                  (char*)sAl + w * 4096 + qI * 1024);
      gload_lds16((const char*)Bh + ((size_t)(bn + row) * ldb + kg) * 2 + src,
                  (char*)sBh + w * 4096 + qI * 1024);
      gload_lds16((const char*)Bl + ((size_t)(bn + row) * ldb + kg) * 2 + src,
                  (char*)sBl + w * 4096 + qI * 1024);
    }
    __syncthreads();
#pragma unroll
    for (int kk = 0; kk < 2; ++kk) {
      bf16x8 ah[4], al[4], bh[4], bl[4];
#pragma unroll
      for (int mi = 0; mi < 4; ++mi) {
        int row = wm + mi * 16 + lr;
        int off = row * 128 + ((kk * 64 + lk * 16) ^ ((row & 7) << 4));
        ah[mi] = *(const bf16x8*)((const char*)sAh + off);
        al[mi] = *(const bf16x8*)((const char*)sAl + off);
      }
#pragma unroll
      for (int ni = 0; ni < 4; ++ni) {
        int row = wn + ni * 16 + lr;
        int off = row * 128 + ((kk * 64 + lk * 16) ^ ((row & 7) << 4));
        bh[ni] = *(const bf16x8*)((const char*)sBh + off);
        bl[ni] = *(const bf16x8*)((const char*)sBl + off);
      }
#pragma unroll
      for (int mi = 0; mi < 4; ++mi)
#pragma unroll
        for (int ni = 0; ni < 4; ++ni) {
          acc[mi][ni] = __builtin_amdgcn_mfma_f32_16x16x32_bf16(ah[mi], bh[ni], acc[mi][ni], 0, 0, 0);
          acc[mi][ni] = __builtin_amdgcn_mfma_f32_16x16x32_bf16(ah[mi], bl[ni], acc[mi][ni], 0, 0, 0);
          acc[mi][ni] = __builtin_amdgcn_mfma_f32_16x16x32_bf16(al[mi], bh[ni], acc[mi][ni], 0, 0, 0);
        }
    }
  }
  float* C = Cp + (size_t)blockIdx.z * 1048576;
#pragma unroll
  for (int mi = 0; mi < 4; ++mi)
#pragma unroll
    for (int j = 0; j < 4; ++j) {
      int row = bm + wm + mi * 16 + lk * 4 + j;
#pragma unroll
      for (int ni = 0; ni < 4; ++ni)
        C[(size_t)row * ldc + bn + wn + ni * 16 + lr] = acc[mi][ni][j];
    }
}

// deterministic 8-way reduce of split-K partials + bf16 copy (1M floats)
__global__ __launch_bounds__(256) void reduce8_cvt(const float* __restrict__ Cp,
    float* __restrict__ vq, ushort* __restrict__ vq_bf)
{
  int i = (blockIdx.x * 256 + threadIdx.x) << 2;
  float4 s = make_float4(0.f, 0.f, 0.f, 0.f);
#pragma unroll
  for (int z = 0; z < 8; ++z) {
    float4 a = *(const float4*)(Cp + (size_t)z * 1048576 + i);
    s.x += a.x; s.y += a.y; s.z += a.z; s.w += a.w;
  }
  *(float4*)(vq + i) = s;
  ushort4 o; o.x = f2bf(s.x); o.y = f2bf(s.y); o.z = f2bf(s.z); o.w = f2bf(s.w);
  *(ushort4*)(vq_bf + i) = o;
}

// ---------------------------------------------------------------------------
// bf16 MFMA GEMM (z-batched): C = A @ Bt^T. 128x128 tile, BK=64.
// 2-phase double-buffered LDS. ROPE=1: fused RoPE epilogue for bn<16.
// ---------------------------------------------------------------------------
template<int OUT_BF16, int ROPE>
__global__ __launch_bounds__(256) void gemm_bf16(
    const ushort* __restrict__ A0, int lda,
    const ushort* __restrict__ Bt0, int ldb,
    void* __restrict__ C0, int ldc, int Kd,
    size_t strA, size_t strB, size_t strC,
    const float* __restrict__ cosb, const float* __restrict__ sinb)
{
  const ushort* A  = A0  + blockIdx.z * strA;
  const ushort* Bt = Bt0 + blockIdx.z * strB;
  __shared__ ushort As[2][128 * 64];
  __shared__ ushort Bs[2][128 * 64];
  const int t = threadIdx.x, w = t >> 6, lane = t & 63;
  const int lr = lane & 15, lk = lane >> 4;
  const int bm = blockIdx.y << 7, bn = blockIdx.x << 7;
  const int wm = (w >> 1) << 6, wn = (w & 1) << 6;
  f32x4 acc[4][4];
#pragma unroll
  for (int i = 0; i < 4; ++i)
#pragma unroll
    for (int j = 0; j < 4; ++j) acc[i][j] = (f32x4){0.f, 0.f, 0.f, 0.f};

#define STAGE_QK(buf, kk0)                                                     \
  {                                                                            \
_Pragma("unroll")                                                              \
    for (int qI = 0; qI < 4; ++qI) {                                           \
      int b = w * 4096 + qI * 1024 + lane * 16;                                \
      int row = b >> 7, colb = b & 127;                                        \
      int src = colb ^ ((row & 7) << 4);                                       \
      gload_lds16((const char*)A + ((size_t)(bm + row) * lda + (kk0)) * 2 + src,\
                  (char*)As[buf] + w * 4096 + qI * 1024);                      \
      gload_lds16((const char*)Bt + ((size_t)(bn + row) * ldb + (kk0)) * 2 + src,\
                  (char*)Bs[buf] + w * 4096 + qI * 1024);                      \
    }                                                                          \
  }

  STAGE_QK(0, 0);
  int cur = 0;
  for (int k0 = 0; k0 < Kd; k0 += 64) {
    __syncthreads();
    if (k0 + 64 < Kd) STAGE_QK(cur ^ 1, k0 + 64);
#pragma unroll
    for (int kk = 0; kk < 2; ++kk) {
      bf16x8 af[4], bf[4];
#pragma unroll
      for (int mi = 0; mi < 4; ++mi) {
        int row = wm + mi * 16 + lr;
        af[mi] = *(const bf16x8*)((const char*)As[cur] + row * 128 + ((kk * 64 + lk * 16) ^ ((row & 7) << 4)));
      }
#pragma unroll
      for (int ni = 0; ni < 4; ++ni) {
        int row = wn + ni * 16 + lr;
        bf[ni] = *(const bf16x8*)((const char*)Bs[cur] + row * 128 + ((kk * 64 + lk * 16) ^ ((row & 7) << 4)));
      }
#pragma unroll
      for (int mi = 0; mi < 4; ++mi)
#pragma unroll
        for (int ni = 0; ni < 4; ++ni)
          acc[mi][ni] = __builtin_amdgcn_mfma_f32_16x16x32_bf16(af[mi], bf[ni], acc[mi][ni], 0, 0, 0);
    }
    cur ^= 1;
  }
#undef STAGE_QK

  if (ROPE && blockIdx.x < 16) {
    __syncthreads();
    ushort* Pl = (ushort*)As;    // [128][128] bf16 = 32 KB
#pragma unroll
    for (int mi = 0; mi < 4; ++mi)
#pragma unroll
      for (int j = 0; j < 4; ++j) {
        int rl = wm + mi * 16 + lk * 4 + j;
#pragma unroll
        for (int ni = 0; ni < 4; ++ni)
          Pl[rl * 128 + wn + ni * 16 + lr] = f2bf(acc[mi][ni][j]);
      }
    __syncthreads();
    const bool lo = (wn == 0);
#pragma unroll
    for (int mi = 0; mi < 4; ++mi)
#pragma unroll
      for (int j = 0; j < 4; ++j) {
        int rl = wm + mi * 16 + lk * 4 + j;
        int row = bm + rl;
#pragma unroll
        for (int ni = 0; ni < 4; ++ni) {
          int d = wn + ni * 16 + lr;
          float a = bf2f(Pl[rl * 128 + d]);
          float b = bf2f(Pl[rl * 128 + (d ^ 64)]);
          float cs = cosb[row * 128 + d], sn = sinb[row * 128 + d];
          float v = lo ? (a * cs - b * sn) : (a * cs + b * sn);
          ((ushort*)C0)[(size_t)row * ldc + bn + d] = f2bf(v);
        }
      }
    return;
  }

#pragma unroll
  for (int mi = 0; mi < 4; ++mi)
#pragma unroll
    for (int j = 0; j < 4; ++j) {
      int row = bm + wm + mi * 16 + lk * 4 + j;
#pragma unroll
      for (int ni = 0; ni < 4; ++ni) {
        int col = bn + wn + ni * 16 + lr;
        if (OUT_BF16) ((ushort*)C0)[blockIdx.z * strC + (size_t)row * ldc + col] = f2bf(acc[mi][ni][j]);
        else          ((float*)C0)[blockIdx.z * strC + (size_t)row * ldc + col]  = acc[mi][ni][j];
      }
    }
}

// ---------------------------------------------------------------------------
// vkeys transpose: dstb (bf16) and dstf (f32), both [hv][n=2048][r=128]
// ---------------------------------------------------------------------------
__global__ __launch_bounds__(256) void transpose_cvt_vk(
    const float* __restrict__ src0, ushort* __restrict__ dstb,
    float* __restrict__ dstf)
{
  const float* src = src0 + (size_t)blockIdx.z * 262144;
  ushort* db = dstb + (size_t)blockIdx.z * 262144;
  float*  df = dstf + (size_t)blockIdx.z * 262144;
  __shared__ float tile[64][65];
  const int r0 = blockIdx.y << 6, c0 = blockIdx.x << 6;
  const int t = threadIdx.x;
  for (int i = t; i < 1024; i += 256) {
    int r = i >> 4, c = (i & 15) << 2;
    float4 v = *(const float4*)(src + (size_t)(r0 + r) * 2048 + c0 + c);
    tile[r][c] = v.x; tile[r][c+1] = v.y; tile[r][c+2] = v.z; tile[r][c+3] = v.w;
  }
  __syncthreads();
  int c = t >> 2, rb = (t & 3) << 4;
#pragma unroll
  for (int u = 0; u < 16; u += 4) {
    float4 f = make_float4(tile[rb+u+0][c], tile[rb+u+1][c],
                           tile[rb+u+2][c], tile[rb+u+3][c]);
    ushort4 o; o.x = f2bf(f.x); o.y = f2bf(f.y); o.z = f2bf(f.z); o.w = f2bf(f.w);
    *(ushort4*)(db + (size_t)(c0 + c) * 128 + r0 + rb + u) = o;
    *(float4*) (df + (size_t)(c0 + c) * 128 + r0 + rb + u) = f;
  }
}

// Wvq transpose -> hi/lo bf16, [512][2048] each. grid (8, 32).
__global__ __launch_bounds__(256) void transpose_cvt_hl(
    const float* __restrict__ src, ushort* __restrict__ dh,
    ushort* __restrict__ dl)
{
  __shared__ float tile[64][65];
  const int r0 = blockIdx.y << 6, c0 = blockIdx.x << 6;
  const int t = threadIdx.x;
  for (int i = t; i < 1024; i += 256) {
    int r = i >> 4, c = (i & 15) << 2;
    float4 v = *(const float4*)(src + (size_t)(r0 + r) * 512 + c0 + c);
    tile[r][c] = v.x; tile[r][c+1] = v.y; tile[r][c+2] = v.z; tile[r][c+3] = v.w;
  }
  __syncthreads();
  int c = t >> 2, rb = (t & 3) << 4;
#pragma unroll
  for (int u = 0; u < 16; u += 4) {
    ushort4 oh, ol;
#pragma unroll
    for (int q = 0; q < 4; ++q) {
      float x = tile[rb + u + q][c];
      ushort hi = f2bf(x);
      ushort lo = f2bf(x - bf2f(hi));
      ((ushort*)&oh)[q] = hi; ((ushort*)&ol)[q] = lo;
    }
    *(ushort4*)(dh + (size_t)(c0 + c) * 2048 + r0 + rb + u) = oh;
    *(ushort4*)(dl + (size_t)(c0 + c) * 2048 + r0 + rb + u) = ol;
  }
}

// triple-source weight transpose: z=0 Wq, z=1 Wk, z=2 Wo (2048x2048 each)
__global__ __launch_bounds__(256) void transpose_cvt_w3(
    const float* __restrict__ srcA, const float* __restrict__ srcB,
    const float* __restrict__ srcC, ushort* __restrict__ dst0)
{
  const float* src = (blockIdx.z == 0) ? srcA : (blockIdx.z == 1) ? srcB : srcC;
  ushort* dst = dst0 + (size_t)blockIdx.z * 4194304;
  __shared__ float tile[64][65];
  const int r0 = blockIdx.y << 6, c0 = blockIdx.x << 6;
  const int t = threadIdx.x;
  for (int i = t; i < 1024; i += 256) {
    int r = i >> 4, c = (i & 15) << 2;
    float4 v = *(const float4*)(src + (size_t)(r0 + r) * 2048 + c0 + c);
    tile[r][c] = v.x; tile[r][c+1] = v.y; tile[r][c+2] = v.z; tile[r][c+3] = v.w;
  }
  __syncthreads();
  int c = t >> 2, rb = (t & 3) << 4;
#pragma unroll
  for (int u = 0; u < 16; u += 4) {
    ushort4 o;
    o.x = f2bf(tile[rb+u+0][c]); o.y = f2bf(tile[rb+u+1][c]);
    o.z = f2bf(tile[rb+u+2][c]); o.w = f2bf(tile[rb+u+3][c]);
    *(ushort4*)(dst + (size_t)(c0 + c) * 2048 + r0 + rb + u) = o;
  }
}

// bf16 -> bf16 transpose (2048x2048)
__global__ __launch_bounds__(256) void transpose_bf(
    const ushort* __restrict__ src, ushort* __restrict__ dst)
{
  __shared__ ushort tile[64][66];
  const int r0 = blockIdx.y << 6, c0 = blockIdx.x << 6;
  const int t = threadIdx.x;
  for (int i = t; i < 512; i += 256) {
    int r = i >> 3, c8 = (i & 7) << 3;
    *(u16x8*)(&tile[r][c8]) = *(const u16x8*)(src + (size_t)(r0 + r) * 2048 + c0 + c8);
  }
  __syncthreads();
  for (int i = t; i < 512; i += 256) {
    int c = i >> 3, r8 = (i & 7) << 3;
    u16x8 o;
#pragma unroll
    for (int u = 0; u < 8; ++u) o[u] = tile[r8 + u][c];
    *(u16x8*)(dst + (size_t)(c0 + c) * 2048 + r0 + r8) = o;
  }
}

// vemb -> bf16; hs -> hi bf16 + lo bf16 (for vq emulation). 3M float4 total.
__global__ __launch_bounds__(256) void cvt3_bf16(const float* __restrict__ vemb,
    ushort* __restrict__ vemb_bf, const float* __restrict__ hs,
    ushort* __restrict__ hs_hi, ushort* __restrict__ hs_lo)
{
  int gid = blockIdx.x * 256 + threadIdx.x;
  if (gid < 1048576) {
    float4 v = ((const float4*)vemb)[gid];
    ushort4 o; o.x = f2bf(v.x); o.y = f2bf(v.y); o.z = f2bf(v.z); o.w = f2bf(v.w);
    ((ushort4*)vemb_bf)[gid] = o;
  } else {
    int i = gid - 1048576;
    float4 v = ((const float4*)hs)[i];
    ushort4 oh, ol;
    float xs[4] = {v.x, v.y, v.z, v.w};
#pragma unroll
    for (int q = 0; q < 4; ++q) {
      ushort hi = f2bf(xs[q]);
      ((ushort*)&oh)[q] = hi;
      ((ushort*)&ol)[q] = f2bf(xs[q] - bf2f(hi));
    }
    ((ushort4*)hs_hi)[i] = oh;
    ((ushort4*)hs_lo)[i] = ol;
  }
}

// ---------------------------------------------------------------------------
// Fused top-k: packed-u32 candidates (sortable-bf16 | 2047-idx), DPP merge,
// exact f32 recompute on contiguous transposed v_keys, exact top-4.
// ---------------------------------------------------------------------------
__global__ __launch_bounds__(256) void topk_sel(const ushort* __restrict__ sim,
    const float* __restrict__ vq, const float* __restrict__ vkTf,
    int* __restrict__ idxo)
{
  const int row = blockIdx.x * 4 + (threadIdx.x >> 6);
  const int hv = row >> 11, s = row & 2047;
  const int lane = threadIdx.x & 63;
  const ushort* r = sim + (size_t)row * 2048;

  unsigned v[8];
#pragma unroll
  for (int p = 0; p < 8; ++p) v[p] = 0u;
  for (int j = 0; j < 4; ++j) {
    int nb = (lane + (j << 6)) << 3;
    u16x8 e = *(const u16x8*)(r + nb);
#pragma unroll
    for (int u = 0; u < 8; ++u) {
      unsigned pk = (bf_sortable(e[u]) << 16) | (unsigned)(2047 - (nb + u));
      if (pk > v[7]) {
        v[7] = pk;
#pragma unroll
        for (int p = 7; p > 0; --p)
          if (v[p] > v[p-1]) { unsigned tt = v[p]; v[p] = v[p-1]; v[p-1] = tt; }
      }
    }
  }
  int out_n[8];
#pragma unroll
  for (int r8 = 0; r8 < 8; ++r8) {
    unsigned m = wave_umax64(v[0]);
    out_n[r8] = 2047 - (int)(m & 0x7FFu);
    if (v[0] == m) {
#pragma unroll
      for (int p = 0; p < 7; ++p) v[p] = v[p+1];
      v[7] = 0u;
    }
  }
  const int c = lane & 7, rc = lane >> 3;
  int n = 0;
#pragma unroll
  for (int p = 0; p < 8; ++p) if (p == c) n = out_n[p];
  const float* vqr = vq + (size_t)s * 512 + hv * 128 + rc * 16;
  const float* vkf = vkTf + (size_t)hv * 262144 + (size_t)n * 128 + rc * 16;
  float acc = 0.f;
#pragma unroll
  for (int u = 0; u < 16; ++u) acc = fmaf(vqr[u], vkf[u], acc);
  acc += __shfl_xor(acc, 8);
  acc += __shfl_xor(acc, 16);
  acc += __shfl_xor(acc, 32);
  float cv = acc; int ci = n;
  int picks[4];
#pragma unroll
  for (int p = 0; p < 4; ++p) {
    float bv = cv; int bi = ci;
#pragma unroll
    for (int d = 1; d < 8; d <<= 1) {
      float ov = __shfl_xor(bv, d); int oi = __shfl_xor(bi, d);
      if (ov > bv || (ov == bv && oi < bi)) { bv = ov; bi = oi; }
    }
    picks[p] = bi;
    if (bi == ci) cv = -FLT_MAX;
  }
  if (lane == 0) {
#pragma unroll
    for (int p = 0; p < 4; ++p) idxo[(size_t)row * 4 + p] = picks[p];
  }
}

// ---------------------------------------------------------------------------
__global__ __launch_bounds__(256) void gather_mul_bf(const float* __restrict__ hs,
    const ushort* __restrict__ vemb_bf, const int* __restrict__ idx,
    ushort* __restrict__ vb)
{
  const int s = blockIdx.x;
  const int t = threadIdx.x;
  __shared__ int id[16];
  if (t < 16) id[t] = idx[((size_t)(t >> 2) * 2048 + s) * 4 + (t & 3)];
  __syncthreads();
  int d0 = t << 3;
  float g[8] = {0.f, 0.f, 0.f, 0.f, 0.f, 0.f, 0.f, 0.f};
#pragma unroll
  for (int e = 0; e < 16; ++e) {
    u16x8 ve = *(const u16x8*)(vemb_bf + (size_t)id[e] * 2048 + d0);
#pragma unroll
    for (int u = 0; u < 8; ++u) g[u] += bf2f(ve[u]);
  }
  float4 h0 = *(const float4*)(hs + (size_t)s * 2048 + d0);
  float4 h1 = *(const float4*)(hs + (size_t)s * 2048 + d0 + 4);
  float hv[8] = {h0.x, h0.y, h0.z, h0.w, h1.x, h1.y, h1.z, h1.w};
  u16x8 o;
#pragma unroll
  for (int u = 0; u < 8; ++u) o[u] = f2bf(hv[u] * g[u]);
  *(u16x8*)(vb + (size_t)s * 2048 + d0) = o;
}

__global__ __launch_bounds__(256) void vmean_part(const ushort* __restrict__ vb,
                                                  float* __restrict__ part)
{
  const int h = blockIdx.y, chunk = blockIdx.x;
  const int t = threadIdx.x, d = t & 127, half = t >> 7;
  float s = 0.f;
  int r0 = chunk * 256 + half * 128;
  for (int r = r0; r < r0 + 128; ++r)
    s += bf2f(vb[(size_t)r * 2048 + h * 128 + d]);
  __shared__ float red[256];
  red[t] = s;
  __syncthreads();
  if (t < 128) part[(size_t)(h * 8 + chunk) * 128 + d] = red[t] + red[t + 128];
}

__global__ __launch_bounds__(256) void vmean_i0(const float* __restrict__ part,
    const float* __restrict__ amask, const float* __restrict__ dmask,
    float* __restrict__ vmean, int* __restrict__ i0)
{
  const int h = blockIdx.x, t = threadIdx.x;
  if (t < 128) {
    float s = 0.f;
#pragma unroll
    for (int c = 0; c < 8; ++c) s += part[(size_t)(h * 8 + c) * 128 + t];
    vmean[h * 128 + t] = s * (1.f / 2048.f);
  }
  int best = 0x7fffffff;
  for (int j = t; j < 2048; j += 256) {
    if (amask[j] * dmask[h * 2048 + j] != 0.f) { best = j; break; }
  }
  __shared__ int red[256];
  red[t] = best;
  __syncthreads();
  for (int off = 128; off > 0; off >>= 1) {
    if (t < off) red[t] = min(red[t], red[t + off]);
    __syncthreads();
  }
  if (t == 0) i0[h] = red[0];
}

// ---------------------------------------------------------------------------
// MFMA flash attention (R16 config): stripe-paired, 8 waves = 2 k-parity
// groups x 4 row waves, double-buffered K/V LDS staging, XCD-swizzled grid,
// exp2 softmax, defer-max + MFMA-l. Measured 56.1 us.
// ---------------------------------------------------------------------------
#define QLD 4096
__global__ __launch_bounds__(512) void attn_mfma(
    const ushort* __restrict__ qb, const ushort* __restrict__ kb,
    const ushort* __restrict__ vt, const float* __restrict__ amask,
    const float* __restrict__ dmask, const float* __restrict__ vmean,
    const int* __restrict__ i0, ushort* __restrict__ ao)
{
  const int L  = blockIdx.x;
  const int pr = L >> 4;                               // pair 0..15
  const int h  = (L & 7) | (((L >> 3) & 1) << 3);      // head; L%8 == h%8
  const int t  = threadIdx.x, w = t >> 6, lane = t & 63;
  const int g  = w >> 2, wg = w & 3;
  const int lr = lane & 15, lk = lane >> 4;

  __shared__ char smem[155648];
  float* accL  = (float*)smem;                      // [64][132] f32 (merge)
  float* smv   = (float*)(smem + 33792);            // [2][64]
  float* slv   = (float*)(smem + 33792 + 512);      // [2][64]
  float* maddL = (float*)(smem + 147456);           // [2048]

  const int i0h = i0[h];

  bf16x8 onesb;
#pragma unroll
  for (int u = 0; u < 8; ++u) onesb[u] = (short)0x3F80;  // bf16 1.0

  for (int j = t; j < 2048; j += 512)
    maddL[j] = (amask[j] * dmask[h * 2048 + j] == 0.f) ? NEG_MIN : 0.f;

  for (int sp = 0; sp < 2; ++sp) {
    const int stripe = (sp == 0) ? pr : 31 - pr;
    const int q0 = stripe << 6;
    const int ntiles = stripe + 1;

    __syncthreads();

    const int qrow = q0 + wg * 16 + lr;
    bf16x8 qf[4];
#pragma unroll
    for (int kk = 0; kk < 4; ++kk)
      qf[kk] = *(const bf16x8*)(qb + (size_t)qrow * QLD + h * 128 + kk * 32 + lk * 8);

    if (g < ntiles) {
      const int c0 = g << 6;
#pragma unroll
      for (int qI = 0; qI < 4; ++qI) {
        int b = wg * 4096 + qI * 1024 + lane * 16;
        int row = b >> 8, colb = b & 255;
        int src = colb ^ ((row & 7) << 4);
        gload_lds16((const char*)kb + ((size_t)(c0 + row) * QLD + h * 128) * 2 + src,
                    smem + g * 32768 + b);
      }
#pragma unroll
      for (int qI = 0; qI < 4; ++qI) {
        int b = wg * 4096 + qI * 1024 + lane * 16;
        int row = b >> 7, colb = b & 127;
        int src = colb ^ ((row & 7) << 4);
        gload_lds16((const char*)vt + ((size_t)(h * 128 + row) * 2048 + c0) * 2 + src,
                    smem + 65536 + g * 32768 + b);
      }
    }

    float m[4];
    f32x4 acc_l = (f32x4){0.f, 0.f, 0.f, 0.f};
    f32x4 acc_o[8];
#pragma unroll
    for (int j = 0; j < 4; ++j) m[j] = -FLT_MAX;
#pragma unroll
    for (int ni = 0; ni < 8; ++ni) acc_o[ni] = (f32x4){0.f, 0.f, 0.f, 0.f};

    int cur = 0;
    const int niter = (ntiles + 1) >> 1;
    for (int it = 0; it < niter; ++it) {
      const int tile = 2 * it + g;
      const int c0 = tile << 6;
      __syncthreads();

      float madd[4];
      if (tile < ntiles) {
#pragma unroll
        for (int ni = 0; ni < 4; ++ni)
          madd[ni] = maddL[c0 + ni * 16 + lr];
      }

      if (tile + 2 < ntiles) {
        const int cn = c0 + 128;
        const int nb = cur ^ 1;
#pragma unroll
        for (int qI = 0; qI < 4; ++qI) {
          int b = wg * 4096 + qI * 1024 + lane * 16;
          int row = b >> 8, colb = b & 255;
          int src = colb ^ ((row & 7) << 4);
          gload_lds16((const char*)kb + ((size_t)(cn + row) * QLD + h * 128) * 2 + src,
                      smem + g * 32768 + nb * 16384 + b);
        }
#pragma unroll
        for (int qI = 0; qI < 4; ++qI) {
          int b = wg * 4096 + qI * 1024 + lane * 16;
          int row = b >> 7, colb = b & 127;
          int src = colb ^ ((row & 7) << 4);
          gload_lds16((const char*)vt + ((size_t)(h * 128 + row) * 2048 + cn) * 2 + src,
                      smem + 65536 + g * 32768 + nb * 16384 + b);
        }
      }

      if (tile < ntiles) {
        const bool diag = (tile == stripe);
        const char* Kbase = smem + g * 32768 + cur * 16384;
        const char* Vbase = smem + 65536 + g * 32768 + cur * 16384;
        char* Pbase = smem + 131072 + g * 8192;

        f32x4 sacc[4];
#pragma unroll
        for (int ni = 0; ni < 4; ++ni) sacc[ni] = (f32x4){0.f, 0.f, 0.f, 0.f};
        __builtin_amdgcn_s_setprio(1);
#pragma unroll
        for (int kk = 0; kk < 4; ++kk) {
#pragma unroll
          for (int ni = 0; ni < 4; ++ni) {
            int krow = ni * 16 + lr;
            bf16x8 bfr = *(const bf16x8*)(Kbase + krow * 256 + ((kk * 64 + lk * 16) ^ ((krow & 7) << 4)));
            sacc[ni] = __builtin_amdgcn_mfma_f32_16x16x32_bf16(qf[kk], bfr, sacc[ni], 0, 0, 0);
          }
        }
        __builtin_amdgcn_s_setprio(0);

        // ---- softmax: defer-max; l from MFMA ones-column (acc_l)
#pragma unroll
        for (int j = 0; j < 4; ++j) {
          int grow = q0 + wg * 16 + lk * 4 + j;
          float x[4];
#pragma unroll
          for (int ni = 0; ni < 4; ++ni) {
            float v = fmaf(sacc[ni][j], SCALE_L2E, madd[ni]);
            if (diag && c0 + ni * 16 + lr > grow) v = NEG_MIN;
            x[ni] = v;
          }
          float pm = fmaxf(fmaxf(x[0], x[1]), fmaxf(x[2], x[3]));
          if (!__all(pm <= m[j] + 16.f)) {
            float tmax = pm;
            tmax = fmaxf(tmax, dpp_ror<0x121>(tmax));
            tmax = fmaxf(tmax, dpp_ror<0x122>(tmax));
            tmax = fmaxf(tmax, dpp_ror<0x124>(tmax));
            tmax = fmaxf(tmax, dpp_ror<0x128>(tmax));
            float mn = fmaxf(m[j], tmax);
            if (mn > m[j]) {
              float sc = exp2f(m[j] - mn);
              acc_l[j] *= sc;
#pragma unroll
              for (int ni = 0; ni < 8; ++ni) acc_o[ni][j] *= sc;
              m[j] = mn;
            }
          }
          int prow = wg * 16 + lk * 4 + j;
#pragma unroll
          for (int ni = 0; ni < 4; ++ni) {
            float p = exp2f(x[ni] - m[j]);
            *(ushort*)(Pbase + prow * 128 + ((2 * (ni * 16 + lr)) ^ ((prow & 7) << 4))) = f2bf(p);
          }
        }

        __builtin_amdgcn_s_setprio(1);
#pragma unroll
        for (int kk = 0; kk < 2; ++kk) {
          int prow = wg * 16 + lr;
          bf16x8 a = *(const bf16x8*)(Pbase + prow * 128 + ((kk * 64 + lk * 16) ^ ((prow & 7) << 4)));
          acc_l = __builtin_amdgcn_mfma_f32_16x16x32_bf16(a, onesb, acc_l, 0, 0, 0);
#pragma unroll
          for (int ni = 0; ni < 8; ++ni) {
            int vrow = ni * 16 + lr;
            bf16x8 bfr = *(const bf16x8*)(Vbase + vrow * 128 + ((kk * 64 + lk * 16) ^ ((vrow & 7) << 4)));
            acc_o[ni] = __builtin_amdgcn_mfma_f32_16x16x32_bf16(a, bfr, acc_o[ni], 0, 0, 0);
          }
        }
        __builtin_amdgcn_s_setprio(0);
      }
      cur ^= 1;
    }

    __syncthreads();
    if (lr == 0) {
#pragma unroll
      for (int j = 0; j < 4; ++j) {
        int r = wg * 16 + lk * 4 + j;
        smv[g * 64 + r] = m[j];
        slv[g * 64 + r] = acc_l[j];
      }
    }
    __syncthreads();
    float myf[4], lcomb[4];
#pragma unroll
    for (int j = 0; j < 4; ++j) {
      int r = wg * 16 + lk * 4 + j;
      float m0 = smv[r], m1 = smv[64 + r];
      float l0 = slv[r], l1 = slv[64 + r];
      float mm = fmaxf(m0, m1);
      float f0 = exp2f(m0 - mm), f1 = exp2f(m1 - mm);
      lcomb[j] = l0 * f0 + l1 * f1;
      myf[j] = (g == 0) ? f0 : f1;
    }
    if (g == 1) {
#pragma unroll
      for (int j = 0; j < 4; ++j) {
        int r = wg * 16 + lk * 4 + j;
#pragma unroll
        for (int ni = 0; ni < 8; ++ni)
          accL[r * 132 + ni * 16 + lr] = acc_o[ni][j] * myf[j];
      }
    }
    __syncthreads();
    if (g == 0) {
#pragma unroll
      for (int j = 0; j < 4; ++j) {
        int row = q0 + wg * 16 + lk * 4 + j;
        int r = wg * 16 + lk * 4 + j;
        if (row < i0h) {
#pragma unroll
          for (int ni = 0; ni < 8; ++ni)
            ao[(size_t)row * 2048 + h * 128 + ni * 16 + lr] = f2bf(vmean[h * 128 + ni * 16 + lr]);
        } else {
          float inv = 1.f / lcomb[j];
#pragma unroll
          for (int ni = 0; ni < 8; ++ni) {
            float o = fmaf(acc_o[ni][j], myf[j], accL[r * 132 + ni * 16 + lr]);
            ao[(size_t)row * 2048 + h * 128 + ni * 16 + lr] = f2bf(o * inv);
          }
        }
      }
    }
  }
}

// ---------------------------------------------------------------------------
extern "C" void kernel_launch(void* const* d_in, const int* in_sizes, int n_in,
                              void* d_out, int out_size, void* d_ws, size_t ws_size,
                              hipStream_t stream)
{
  const float* hs    = (const float*)d_in[0];
  const float* amask = (const float*)d_in[1];
  const float* cosb  = (const float*)d_in[2];
  const float* sinb  = (const float*)d_in[3];
  const float* dmask = (const float*)d_in[4];
  const float* Wq    = (const float*)d_in[5];
  const float* Wk    = (const float*)d_in[6];
  const float* Wvq   = (const float*)d_in[7];
  const float* vkeys = (const float*)d_in[8];
  const float* vemb  = (const float*)d_in[9];
  const float* Wo    = (const float*)d_in[10];
  float* outp = (float*)d_out;

  char* ws = (char*)d_ws;
  const size_t MB = 1048576;
  float*  pvq     = (float*) (ws + 0);              // A: [0,32) 8 partials
  ushort* WvqTh   = (ushort*)(ws + 32*MB);          // A: [32,34)
  ushort* WvqTl   = (ushort*)(ws + 34*MB);          // A: [34,36)
  ushort* hs_lo   = (ushort*)(ws + 55*MB);          // A: [55,63)
  float*  vq_f32  = (float*) (ws + 64*MB);          // A-B: [64,68)
  ushort* vq_bf   = (ushort*)(ws + 68*MB);          // A-B: [68,70)
  ushort* vkT     = (ushort*)(ws + 0);              // B: [0,2)   over dead pvq
  ushort* sim_bf  = (ushort*)(ws + 2*MB);           // B: [2,34)
  int*    idx     = (int*)   (ws + 34*MB);          // B-C: 128 KB
  float*  vkTf32  = (float*) (ws + 36*MB);          // B: [36,40)
  ushort* vemb_bf = (ushort*)(ws + 70*MB);          // A-C: [70,78)
  ushort* hs_bf   = (ushort*)(ws + 43*MB);          // A-D: [43,51)
  ushort* vb      = (ushort*)(ws + 0);              // C: [0,8)
  ushort* vt      = (ushort*)(ws + 8*MB);           // C-E: [8,16)
  float*  part    = (float*) (ws + 51*MB);          // C: 64 KB
  float*  vmean   = (float*) (ws + 51*MB + 65536);  // C-E: 8 KB
  int*    i0b     = (int*)   (ws + 51*MB + 73728);  // C-E: 64 B
  ushort* WBig    = (ushort*)(ws + 16*MB);          // D-E: [16,40) Wq|Wk|Wo^T
  ushort* WoT     = (ushort*)(ws + 32*MB);          // = WBig + 16MB
  ushort* qkC     = (ushort*)(ws + 52*MB);          // D-E: [52,68) q|k, ld 4096
  ushort* ao      = (ushort*)(ws + 0);              // E: [0,8)

  dim3 blk(256);
  // ---- prep: conversions + Wvq hi/lo transpose ----
  cvt3_bf16<<<dim3(8192), blk, 0, stream>>>(vemb, vemb_bf, hs, hs_bf, hs_lo);
  transpose_cvt_hl<<<dim3(8, 32), blk, 0, stream>>>(Wvq, WvqTh, WvqTl);
  // ---- routing path: vq via 3-term bf16 MFMA emulation ----
  gemm_vq3<<<dim3(4, 16, 8), blk, 0, stream>>>(hs_bf, hs_lo, 2048,
      WvqTh, WvqTl, 2048, pvq, 512, 256);
  reduce8_cvt<<<dim3(1024), blk, 0, stream>>>(pvq, vq_f32, vq_bf);
  transpose_cvt_vk<<<dim3(32, 2, 4), blk, 0, stream>>>(vkeys, vkT, vkTf32);
  gemm_bf16<1, 0><<<dim3(16, 16, 4), blk, 0, stream>>>(vq_bf, 512, vkT, 128,
      sim_bf, 2048, 128, 128, 262144, 4194304, nullptr, nullptr);
  topk_sel<<<dim3(2048), blk, 0, stream>>>(sim_bf, vq_f32, vkTf32, idx);
  // ---- v construction ----
  gather_mul_bf<<<dim3(2048), blk, 0, stream>>>(hs, vemb_bf, idx, vb);
  transpose_bf<<<dim3(32, 32), blk, 0, stream>>>(vb, vt);
  vmean_part<<<dim3(8, 16), blk, 0, stream>>>(vb, part);
  vmean_i0<<<dim3(16), blk, 0, stream>>>(part, amask, dmask, vmean, i0b);
  // ---- projections: Wq|Wk|Wo transpose (z=3), fused qk GEMM + RoPE ----
  transpose_cvt_w3<<<dim3(32, 32, 3), blk, 0, stream>>>(Wq, Wk, Wo, WBig);
  gemm_bf16<1, 1><<<dim3(32, 16, 1), blk, 0, stream>>>(hs_bf, 2048, WBig, 2048,
      qkC, 4096, 2048, 0, 0, 0, cosb, sinb);
  // ---- attention (XCD-swizzled 1D grid) ----
  attn_mfma<<<dim3(256), dim3(512), 0, stream>>>(qkC, qkC + 2048, vt, amask, dmask, vmean, i0b, ao);
  // ---- output projection ----
  gemm_bf16<0, 0><<<dim3(16, 16, 1), blk, 0, stream>>>(ao, 2048, WoT, 2048,
      outp, 2048, 2048, 0, 0, 0, nullptr, nullptr);
}

// Round 21
// 281.889 us; speedup vs baseline: 1.5438x; 1.0274x over previous
//
#include <hip/hip_runtime.h>
#include <float.h>

// B=1, S=2048, D=2048, H=16, HD=128, HV=4, R=128, NV=2048, K=4
#define NEG_MIN (-3.4028234663852886e38f)
#define INV_SQRT_HD 0.08838834764831845f
#define SCALE_L2E 0.12751791437968458f    // INV_SQRT_HD * log2(e)

typedef __attribute__((ext_vector_type(8))) short bf16x8;
typedef __attribute__((ext_vector_type(8))) unsigned short u16x8;
typedef __attribute__((ext_vector_type(4))) float f32x4;

__device__ __forceinline__ void gload_lds16(const void* g, void* l) {
  __builtin_amdgcn_global_load_lds((const __attribute__((address_space(1))) void*)g,
                                   (__attribute__((address_space(3))) void*)l, 16, 0, 0);
}
__device__ __forceinline__ ushort f2bf(float x) {
  union { float f; unsigned u; } v; v.f = x;
  unsigned r = v.u + 0x7fffu + ((v.u >> 16) & 1u);   // RNE
  return (ushort)(r >> 16);
}
__device__ __forceinline__ float bf2f(ushort u) {
  union { unsigned i; float f; } v; v.i = ((unsigned)u) << 16; return v.f;
}
template<int CTRL>
__device__ __forceinline__ float dpp_ror(float x) {
  return __int_as_float(__builtin_amdgcn_mov_dpp(__float_as_int(x), CTRL, 0xF, 0xF, true));
}
template<int CTRL>
__device__ __forceinline__ unsigned dpp_ror_u(unsigned x) {
  return (unsigned)__builtin_amdgcn_mov_dpp((int)x, CTRL, 0xF, 0xF, true);
}
__device__ __forceinline__ unsigned wave_umax64(unsigned x) {
  x = max(x, dpp_ror_u<0x121>(x));
  x = max(x, dpp_ror_u<0x122>(x));
  x = max(x, dpp_ror_u<0x124>(x));
  x = max(x, dpp_ror_u<0x128>(x));
  x = max(x, (unsigned)__shfl_xor((int)x, 16));
  x = max(x, (unsigned)__shfl_xor((int)x, 32));
  return x;
}
__device__ __forceinline__ unsigned bf_sortable(ushort b) {
  return (b & 0x8000u) ? (unsigned)(b ^ 0xFFFFu) : (unsigned)(b | 0x8000u);
}

// ---------------------------------------------------------------------------
// vq via 3-term bf16 emulation of f32 GEMM (MFMA pipe, rel err ~8e-6)
// ---------------------------------------------------------------------------
__global__ __launch_bounds__(256) void gemm_vq3(
    const ushort* __restrict__ Ah, const ushort* __restrict__ Al, int lda,
    const ushort* __restrict__ Bh, const ushort* __restrict__ Bl, int ldb,
    float* __restrict__ Cp, int ldc, int Kchunk)
{
  __shared__ ushort sAh[128 * 64], sAl[128 * 64];
  __shared__ ushort sBh[128 * 64], sBl[128 * 64];
  const int t = threadIdx.x, w = t >> 6, lane = t & 63;
  const int lr = lane & 15, lk = lane >> 4;
  const int bm = blockIdx.y << 7, bn = blockIdx.x << 7;
  const int k0base = blockIdx.z * Kchunk;
  const int wm = (w >> 1) << 6, wn = (w & 1) << 6;
  f32x4 acc[4][4];
#pragma unroll
  for (int i = 0; i < 4; ++i)
#pragma unroll
    for (int j = 0; j < 4; ++j) acc[i][j] = (f32x4){0.f, 0.f, 0.f, 0.f};

  for (int k0 = 0; k0 < Kchunk; k0 += 64) {
    const int kg = k0base + k0;
    __syncthreads();
#pragma unroll
    for (int qI = 0; qI < 4; ++qI) {
      int b = w * 4096 + qI * 1024 + lane * 16;
      int row = b >> 7, colb = b & 127;
      int src = colb ^ ((row & 7) << 4);
      gload_lds16((const char*)Ah + ((size_t)(bm + row) * lda + kg) * 2 + src,
                  (char*)sAh + w * 4096 + qI * 1024);
      gload_lds16((const char*)Al + ((size_t)(bm + row) * lda + kg) * 2 + src,
                  (char*)sAl + w * 4096 + qI * 1024);
      gload_lds16((const char*)Bh + ((size_t)(bn + row) * ldb + kg) * 2 + src,
                  (char*)sBh + w * 4096 + qI * 1024);
      gload_lds16((const char*)Bl + ((size_t)(bn + row) * ldb + kg) * 2 + src,
                  (char*)sBl + w * 4096 + qI * 1024);
    }
    __syncthreads();
#pragma unroll
    for (int kk = 0; kk < 2; ++kk) {
      bf16x8 ah[4], al[4], bh[4], bl[4];
#pragma unroll
      for (int mi = 0; mi < 4; ++mi) {
        int row = wm + mi * 16 + lr;
        int off = row * 128 + ((kk * 64 + lk * 16) ^ ((row & 7) << 4));
        ah[mi] = *(const bf16x8*)((const char*)sAh + off);
        al[mi] = *(const bf16x8*)((const char*)sAl + off);
      }
#pragma unroll
      for (int ni = 0; ni < 4; ++ni) {
        int row = wn + ni * 16 + lr;
        int off = row * 128 + ((kk * 64 + lk * 16) ^ ((row & 7) << 4));
        bh[ni] = *(const bf16x8*)((const char*)sBh + off);
        bl[ni] = *(const bf16x8*)((const char*)sBl + off);
      }
#pragma unroll
      for (int mi = 0; mi < 4; ++mi)
#pragma unroll
        for (int ni = 0; ni < 4; ++ni) {
          acc[mi][ni] = __builtin_amdgcn_mfma_f32_16x16x32_bf16(ah[mi], bh[ni], acc[mi][ni], 0, 0, 0);
          acc[mi][ni] = __builtin_amdgcn_mfma_f32_16x16x32_bf16(ah[mi], bl[ni], acc[mi][ni], 0, 0, 0);
          acc[mi][ni] = __builtin_amdgcn_mfma_f32_16x16x32_bf16(al[mi], bh[ni], acc[mi][ni], 0, 0, 0);
        }
    }
  }
  float* C = Cp + (size_t)blockIdx.z * 1048576;
#pragma unroll
  for (int mi = 0; mi < 4; ++mi)
#pragma unroll
    for (int j = 0; j < 4; ++j) {
      int row = bm + wm + mi * 16 + lk * 4 + j;
#pragma unroll
      for (int ni = 0; ni < 4; ++ni)
        C[(size_t)row * ldc + bn + wn + ni * 16 + lr] = acc[mi][ni][j];
    }
}

// deterministic 8-way reduce of split-K partials + bf16 copy (1M floats)
__global__ __launch_bounds__(256) void reduce8_cvt(const float* __restrict__ Cp,
    float* __restrict__ vq, ushort* __restrict__ vq_bf)
{
  int i = (blockIdx.x * 256 + threadIdx.x) << 2;
  float4 s = make_float4(0.f, 0.f, 0.f, 0.f);
#pragma unroll
  for (int z = 0; z < 8; ++z) {
    float4 a = *(const float4*)(Cp + (size_t)z * 1048576 + i);
    s.x += a.x; s.y += a.y; s.z += a.z; s.w += a.w;
  }
  *(float4*)(vq + i) = s;
  ushort4 o; o.x = f2bf(s.x); o.y = f2bf(s.y); o.z = f2bf(s.z); o.w = f2bf(s.w);
  *(ushort4*)(vq_bf + i) = o;
}

// ---------------------------------------------------------------------------
// bf16 MFMA GEMM (z-batched): C = A @ Bt^T. 128x128 tile, BK=64.
// 2-phase double-buffered LDS. ROPE=1: fused RoPE epilogue for bn<16.
// ---------------------------------------------------------------------------
template<int OUT_BF16, int ROPE>
__global__ __launch_bounds__(256) void gemm_bf16(
    const ushort* __restrict__ A0, int lda,
    const ushort* __restrict__ Bt0, int ldb,
    void* __restrict__ C0, int ldc, int Kd,
    size_t strA, size_t strB, size_t strC,
    const float* __restrict__ cosb, const float* __restrict__ sinb)
{
  const ushort* A  = A0  + blockIdx.z * strA;
  const ushort* Bt = Bt0 + blockIdx.z * strB;
  __shared__ ushort As[2][128 * 64];
  __shared__ ushort Bs[2][128 * 64];
  const int t = threadIdx.x, w = t >> 6, lane = t & 63;
  const int lr = lane & 15, lk = lane >> 4;
  const int bm = blockIdx.y << 7, bn = blockIdx.x << 7;
  const int wm = (w >> 1) << 6, wn = (w & 1) << 6;
  f32x4 acc[4][4];
#pragma unroll
  for (int i = 0; i < 4; ++i)
#pragma unroll
    for (int j = 0; j < 4; ++j) acc[i][j] = (f32x4){0.f, 0.f, 0.f, 0.f};

#define STAGE_QK(buf, kk0)                                                     \
  {                                                                            \
_Pragma("unroll")                                                              \
    for (int qI = 0; qI < 4; ++qI) {                                           \
      int b = w * 4096 + qI * 1024 + lane * 16;                                \
      int row = b >> 7, colb = b & 127;                                        \
      int src = colb ^ ((row & 7) << 4);                                       \
      gload_lds16((const char*)A + ((size_t)(bm + row) * lda + (kk0)) * 2 + src,\
                  (char*)As[buf] + w * 4096 + qI * 1024);                      \
      gload_lds16((const char*)Bt + ((size_t)(bn + row) * ldb + (kk0)) * 2 + src,\
                  (char*)Bs[buf] + w * 4096 + qI * 1024);                      \
    }                                                                          \
  }

  STAGE_QK(0, 0);
  int cur = 0;
  for (int k0 = 0; k0 < Kd; k0 += 64) {
    __syncthreads();
    if (k0 + 64 < Kd) STAGE_QK(cur ^ 1, k0 + 64);
#pragma unroll
    for (int kk = 0; kk < 2; ++kk) {
      bf16x8 af[4], bf[4];
#pragma unroll
      for (int mi = 0; mi < 4; ++mi) {
        int row = wm + mi * 16 + lr;
        af[mi] = *(const bf16x8*)((const char*)As[cur] + row * 128 + ((kk * 64 + lk * 16) ^ ((row & 7) << 4)));
      }
#pragma unroll
      for (int ni = 0; ni < 4; ++ni) {
        int row = wn + ni * 16 + lr;
        bf[ni] = *(const bf16x8*)((const char*)Bs[cur] + row * 128 + ((kk * 64 + lk * 16) ^ ((row & 7) << 4)));
      }
#pragma unroll
      for (int mi = 0; mi < 4; ++mi)
#pragma unroll
        for (int ni = 0; ni < 4; ++ni)
          acc[mi][ni] = __builtin_amdgcn_mfma_f32_16x16x32_bf16(af[mi], bf[ni], acc[mi][ni], 0, 0, 0);
    }
    cur ^= 1;
  }
#undef STAGE_QK

  if (ROPE && blockIdx.x < 16) {
    __syncthreads();
    ushort* Pl = (ushort*)As;    // [128][128] bf16 = 32 KB
#pragma unroll
    for (int mi = 0; mi < 4; ++mi)
#pragma unroll
      for (int j = 0; j < 4; ++j) {
        int rl = wm + mi * 16 + lk * 4 + j;
#pragma unroll
        for (int ni = 0; ni < 4; ++ni)
          Pl[rl * 128 + wn + ni * 16 + lr] = f2bf(acc[mi][ni][j]);
      }
    __syncthreads();
    const bool lo = (wn == 0);
#pragma unroll
    for (int mi = 0; mi < 4; ++mi)
#pragma unroll
      for (int j = 0; j < 4; ++j) {
        int rl = wm + mi * 16 + lk * 4 + j;
        int row = bm + rl;
#pragma unroll
        for (int ni = 0; ni < 4; ++ni) {
          int d = wn + ni * 16 + lr;
          float a = bf2f(Pl[rl * 128 + d]);
          float b = bf2f(Pl[rl * 128 + (d ^ 64)]);
          float cs = cosb[row * 128 + d], sn = sinb[row * 128 + d];
          float v = lo ? (a * cs - b * sn) : (a * cs + b * sn);
          ((ushort*)C0)[(size_t)row * ldc + bn + d] = f2bf(v);
        }
      }
    return;
  }

#pragma unroll
  for (int mi = 0; mi < 4; ++mi)
#pragma unroll
    for (int j = 0; j < 4; ++j) {
      int row = bm + wm + mi * 16 + lk * 4 + j;
#pragma unroll
      for (int ni = 0; ni < 4; ++ni) {
        int col = bn + wn + ni * 16 + lr;
        if (OUT_BF16) ((ushort*)C0)[blockIdx.z * strC + (size_t)row * ldc + col] = f2bf(acc[mi][ni][j]);
        else          ((float*)C0)[blockIdx.z * strC + (size_t)row * ldc + col]  = acc[mi][ni][j];
      }
    }
}

// ---------------------------------------------------------------------------
// bf16 MFMA GEMM, 128x64 tile (N-split): doubles grid for M=N=2048 shapes
// (out projection was 256 blocks = 1 block/CU = grid-starved). 4 waves in
// 2x2 quadrants of 64x32; acc 4x2 frags. f32 output only.
// ---------------------------------------------------------------------------
__global__ __launch_bounds__(256) void gemm_bf16_n64(
    const ushort* __restrict__ A, int lda,
    const ushort* __restrict__ Bt, int ldb,
    float* __restrict__ C, int ldc, int Kd)
{
  __shared__ ushort As[2][128 * 64];
  __shared__ ushort Bs[2][64 * 64];
  const int t = threadIdx.x, w = t >> 6, lane = t & 63;
  const int lr = lane & 15, lk = lane >> 4;
  const int bm = blockIdx.y << 7, bn = blockIdx.x << 6;
  const int wm = (w >> 1) << 6, wn = (w & 1) << 5;   // 64x32 per wave
  f32x4 acc[4][2];
#pragma unroll
  for (int i = 0; i < 4; ++i)
#pragma unroll
    for (int j = 0; j < 2; ++j) acc[i][j] = (f32x4){0.f, 0.f, 0.f, 0.f};

#define STAGE_N64(buf, kk0)                                                    \
  {                                                                            \
_Pragma("unroll")                                                              \
    for (int qI = 0; qI < 4; ++qI) {                                           \
      int b = w * 4096 + qI * 1024 + lane * 16;                                \
      int row = b >> 7, colb = b & 127;                                        \
      int src = colb ^ ((row & 7) << 4);                                       \
      gload_lds16((const char*)A + ((size_t)(bm + row) * lda + (kk0)) * 2 + src,\
                  (char*)As[buf] + w * 4096 + qI * 1024);                      \
    }                                                                          \
_Pragma("unroll")                                                              \
    for (int qI = 0; qI < 2; ++qI) {                                           \
      int b = qI * 4096 + w * 1024 + lane * 16;                                \
      int row = b >> 7, colb = b & 127;                                        \
      int src = colb ^ ((row & 7) << 4);                                       \
      gload_lds16((const char*)Bt + ((size_t)(bn + row) * ldb + (kk0)) * 2 + src,\
                  (char*)Bs[buf] + qI * 4096 + w * 1024);                      \
    }                                                                          \
  }

  STAGE_N64(0, 0);
  int cur = 0;
  for (int k0 = 0; k0 < Kd; k0 += 64) {
    __syncthreads();
    if (k0 + 64 < Kd) STAGE_N64(cur ^ 1, k0 + 64);
#pragma unroll
    for (int kk = 0; kk < 2; ++kk) {
      bf16x8 af[4], bf[2];
#pragma unroll
      for (int mi = 0; mi < 4; ++mi) {
        int row = wm + mi * 16 + lr;
        af[mi] = *(const bf16x8*)((const char*)As[cur] + row * 128 + ((kk * 64 + lk * 16) ^ ((row & 7) << 4)));
      }
#pragma unroll
      for (int ni = 0; ni < 2; ++ni) {
        int row = wn + ni * 16 + lr;
        bf[ni] = *(const bf16x8*)((const char*)Bs[cur] + row * 128 + ((kk * 64 + lk * 16) ^ ((row & 7) << 4)));
      }
#pragma unroll
      for (int mi = 0; mi < 4; ++mi)
#pragma unroll
        for (int ni = 0; ni < 2; ++ni)
          acc[mi][ni] = __builtin_amdgcn_mfma_f32_16x16x32_bf16(af[mi], bf[ni], acc[mi][ni], 0, 0, 0);
    }
    cur ^= 1;
  }
#undef STAGE_N64

#pragma unroll
  for (int mi = 0; mi < 4; ++mi)
#pragma unroll
    for (int j = 0; j < 4; ++j) {
      int row = bm + wm + mi * 16 + lk * 4 + j;
#pragma unroll
      for (int ni = 0; ni < 2; ++ni)
        C[(size_t)row * ldc + bn + wn + ni * 16 + lr] = acc[mi][ni][j];
    }
}

// ---------------------------------------------------------------------------
// vkeys transpose: dstb (bf16) and dstf (f32), both [hv][n=2048][r=128]
// ---------------------------------------------------------------------------
__global__ __launch_bounds__(256) void transpose_cvt_vk(
    const float* __restrict__ src0, ushort* __restrict__ dstb,
    float* __restrict__ dstf)
{
  const float* src = src0 + (size_t)blockIdx.z * 262144;
  ushort* db = dstb + (size_t)blockIdx.z * 262144;
  float*  df = dstf + (size_t)blockIdx.z * 262144;
  __shared__ float tile[64][65];
  const int r0 = blockIdx.y << 6, c0 = blockIdx.x << 6;
  const int t = threadIdx.x;
  for (int i = t; i < 1024; i += 256) {
    int r = i >> 4, c = (i & 15) << 2;
    float4 v = *(const float4*)(src + (size_t)(r0 + r) * 2048 + c0 + c);
    tile[r][c] = v.x; tile[r][c+1] = v.y; tile[r][c+2] = v.z; tile[r][c+3] = v.w;
  }
  __syncthreads();
  int c = t >> 2, rb = (t & 3) << 4;
#pragma unroll
  for (int u = 0; u < 16; u += 4) {
    float4 f = make_float4(tile[rb+u+0][c], tile[rb+u+1][c],
                           tile[rb+u+2][c], tile[rb+u+3][c]);
    ushort4 o; o.x = f2bf(f.x); o.y = f2bf(f.y); o.z = f2bf(f.z); o.w = f2bf(f.w);
    *(ushort4*)(db + (size_t)(c0 + c) * 128 + r0 + rb + u) = o;
    *(float4*) (df + (size_t)(c0 + c) * 128 + r0 + rb + u) = f;
  }
}

// Wvq transpose -> hi/lo bf16, [512][2048] each. grid (8, 32).
__global__ __launch_bounds__(256) void transpose_cvt_hl(
    const float* __restrict__ src, ushort* __restrict__ dh,
    ushort* __restrict__ dl)
{
  __shared__ float tile[64][65];
  const int r0 = blockIdx.y << 6, c0 = blockIdx.x << 6;
  const int t = threadIdx.x;
  for (int i = t; i < 1024; i += 256) {
    int r = i >> 4, c = (i & 15) << 2;
    float4 v = *(const float4*)(src + (size_t)(r0 + r) * 512 + c0 + c);
    tile[r][c] = v.x; tile[r][c+1] = v.y; tile[r][c+2] = v.z; tile[r][c+3] = v.w;
  }
  __syncthreads();
  int c = t >> 2, rb = (t & 3) << 4;
#pragma unroll
  for (int u = 0; u < 16; u += 4) {
    ushort4 oh, ol;
#pragma unroll
    for (int q = 0; q < 4; ++q) {
      float x = tile[rb + u + q][c];
      ushort hi = f2bf(x);
      ushort lo = f2bf(x - bf2f(hi));
      ((ushort*)&oh)[q] = hi; ((ushort*)&ol)[q] = lo;
    }
    *(ushort4*)(dh + (size_t)(c0 + c) * 2048 + r0 + rb + u) = oh;
    *(ushort4*)(dl + (size_t)(c0 + c) * 2048 + r0 + rb + u) = ol;
  }
}

// triple-source weight transpose: z=0 Wq, z=1 Wk, z=2 Wo (2048x2048 each)
__global__ __launch_bounds__(256) void transpose_cvt_w3(
    const float* __restrict__ srcA, const float* __restrict__ srcB,
    const float* __restrict__ srcC, ushort* __restrict__ dst0)
{
  const float* src = (blockIdx.z == 0) ? srcA : (blockIdx.z == 1) ? srcB : srcC;
  ushort* dst = dst0 + (size_t)blockIdx.z * 4194304;
  __shared__ float tile[64][65];
  const int r0 = blockIdx.y << 6, c0 = blockIdx.x << 6;
  const int t = threadIdx.x;
  for (int i = t; i < 1024; i += 256) {
    int r = i >> 4, c = (i & 15) << 2;
    float4 v = *(const float4*)(src + (size_t)(r0 + r) * 2048 + c0 + c);
    tile[r][c] = v.x; tile[r][c+1] = v.y; tile[r][c+2] = v.z; tile[r][c+3] = v.w;
  }
  __syncthreads();
  int c = t >> 2, rb = (t & 3) << 4;
#pragma unroll
  for (int u = 0; u < 16; u += 4) {
    ushort4 o;
    o.x = f2bf(tile[rb+u+0][c]); o.y = f2bf(tile[rb+u+1][c]);
    o.z = f2bf(tile[rb+u+2][c]); o.w = f2bf(tile[rb+u+3][c]);
    *(ushort4*)(dst + (size_t)(c0 + c) * 2048 + r0 + rb + u) = o;
  }
}

// bf16 -> bf16 transpose (2048x2048)
__global__ __launch_bounds__(256) void transpose_bf(
    const ushort* __restrict__ src, ushort* __restrict__ dst)
{
  __shared__ ushort tile[64][66];
  const int r0 = blockIdx.y << 6, c0 = blockIdx.x << 6;
  const int t = threadIdx.x;
  for (int i = t; i < 512; i += 256) {
    int r = i >> 3, c8 = (i & 7) << 3;
    *(u16x8*)(&tile[r][c8]) = *(const u16x8*)(src + (size_t)(r0 + r) * 2048 + c0 + c8);
  }
  __syncthreads();
  for (int i = t; i < 512; i += 256) {
    int c = i >> 3, r8 = (i & 7) << 3;
    u16x8 o;
#pragma unroll
    for (int u = 0; u < 8; ++u) o[u] = tile[r8 + u][c];
    *(u16x8*)(dst + (size_t)(c0 + c) * 2048 + r0 + r8) = o;
  }
}

// vemb -> bf16; hs -> hi bf16 + lo bf16 (for vq emulation). 3M float4 total.
__global__ __launch_bounds__(256) void cvt3_bf16(const float* __restrict__ vemb,
    ushort* __restrict__ vemb_bf, const float* __restrict__ hs,
    ushort* __restrict__ hs_hi, ushort* __restrict__ hs_lo)
{
  int gid = blockIdx.x * 256 + threadIdx.x;
  if (gid < 1048576) {
    float4 v = ((const float4*)vemb)[gid];
    ushort4 o; o.x = f2bf(v.x); o.y = f2bf(v.y); o.z = f2bf(v.z); o.w = f2bf(v.w);
    ((ushort4*)vemb_bf)[gid] = o;
  } else {
    int i = gid - 1048576;
    float4 v = ((const float4*)hs)[i];
    ushort4 oh, ol;
    float xs[4] = {v.x, v.y, v.z, v.w};
#pragma unroll
    for (int q = 0; q < 4; ++q) {
      ushort hi = f2bf(xs[q]);
      ((ushort*)&oh)[q] = hi;
      ((ushort*)&ol)[q] = f2bf(xs[q] - bf2f(hi));
    }
    ((ushort4*)hs_hi)[i] = oh;
    ((ushort4*)hs_lo)[i] = ol;
  }
}

// ---------------------------------------------------------------------------
// Fused top-k: packed-u32 candidates (sortable-bf16 | 2047-idx), DPP merge,
// exact f32 recompute on contiguous transposed v_keys, exact top-4.
// ---------------------------------------------------------------------------
__global__ __launch_bounds__(256) void topk_sel(const ushort* __restrict__ sim,
    const float* __restrict__ vq, const float* __restrict__ vkTf,
    int* __restrict__ idxo)
{
  const int row = blockIdx.x * 4 + (threadIdx.x >> 6);
  const int hv = row >> 11, s = row & 2047;
  const int lane = threadIdx.x & 63;
  const ushort* r = sim + (size_t)row * 2048;

  unsigned v[8];
#pragma unroll
  for (int p = 0; p < 8; ++p) v[p] = 0u;
  for (int j = 0; j < 4; ++j) {
    int nb = (lane + (j << 6)) << 3;
    u16x8 e = *(const u16x8*)(r + nb);
#pragma unroll
    for (int u = 0; u < 8; ++u) {
      unsigned pk = (bf_sortable(e[u]) << 16) | (unsigned)(2047 - (nb + u));
      if (pk > v[7]) {
        v[7] = pk;
#pragma unroll
        for (int p = 7; p > 0; --p)
          if (v[p] > v[p-1]) { unsigned tt = v[p]; v[p] = v[p-1]; v[p-1] = tt; }
      }
    }
  }
  int out_n[8];
#pragma unroll
  for (int r8 = 0; r8 < 8; ++r8) {
    unsigned m = wave_umax64(v[0]);
    out_n[r8] = 2047 - (int)(m & 0x7FFu);
    if (v[0] == m) {
#pragma unroll
      for (int p = 0; p < 7; ++p) v[p] = v[p+1];
      v[7] = 0u;
    }
  }
  const int c = lane & 7, rc = lane >> 3;
  int n = 0;
#pragma unroll
  for (int p = 0; p < 8; ++p) if (p == c) n = out_n[p];
  const float* vqr = vq + (size_t)s * 512 + hv * 128 + rc * 16;
  const float* vkf = vkTf + (size_t)hv * 262144 + (size_t)n * 128 + rc * 16;
  float acc = 0.f;
#pragma unroll
  for (int u = 0; u < 16; ++u) acc = fmaf(vqr[u], vkf[u], acc);
  acc += __shfl_xor(acc, 8);
  acc += __shfl_xor(acc, 16);
  acc += __shfl_xor(acc, 32);
  float cv = acc; int ci = n;
  int picks[4];
#pragma unroll
  for (int p = 0; p < 4; ++p) {
    float bv = cv; int bi = ci;
#pragma unroll
    for (int d = 1; d < 8; d <<= 1) {
      float ov = __shfl_xor(bv, d); int oi = __shfl_xor(bi, d);
      if (ov > bv || (ov == bv && oi < bi)) { bv = ov; bi = oi; }
    }
    picks[p] = bi;
    if (bi == ci) cv = -FLT_MAX;
  }
  if (lane == 0) {
#pragma unroll
    for (int p = 0; p < 4; ++p) idxo[(size_t)row * 4 + p] = picks[p];
  }
}

// ---------------------------------------------------------------------------
__global__ __launch_bounds__(256) void gather_mul_bf(const float* __restrict__ hs,
    const ushort* __restrict__ vemb_bf, const int* __restrict__ idx,
    ushort* __restrict__ vb)
{
  const int s = blockIdx.x;
  const int t = threadIdx.x;
  __shared__ int id[16];
  if (t < 16) id[t] = idx[((size_t)(t >> 2) * 2048 + s) * 4 + (t & 3)];
  __syncthreads();
  int d0 = t << 3;
  float g[8] = {0.f, 0.f, 0.f, 0.f, 0.f, 0.f, 0.f, 0.f};
#pragma unroll
  for (int e = 0; e < 16; ++e) {
    u16x8 ve = *(const u16x8*)(vemb_bf + (size_t)id[e] * 2048 + d0);
#pragma unroll
    for (int u = 0; u < 8; ++u) g[u] += bf2f(ve[u]);
  }
  float4 h0 = *(const float4*)(hs + (size_t)s * 2048 + d0);
  float4 h1 = *(const float4*)(hs + (size_t)s * 2048 + d0 + 4);
  float hv[8] = {h0.x, h0.y, h0.z, h0.w, h1.x, h1.y, h1.z, h1.w};
  u16x8 o;
#pragma unroll
  for (int u = 0; u < 8; ++u) o[u] = f2bf(hv[u] * g[u]);
  *(u16x8*)(vb + (size_t)s * 2048 + d0) = o;
}

__global__ __launch_bounds__(256) void vmean_part(const ushort* __restrict__ vb,
                                                  float* __restrict__ part)
{
  const int h = blockIdx.y, chunk = blockIdx.x;
  const int t = threadIdx.x, d = t & 127, half = t >> 7;
  float s = 0.f;
  int r0 = chunk * 256 + half * 128;
  for (int r = r0; r < r0 + 128; ++r)
    s += bf2f(vb[(size_t)r * 2048 + h * 128 + d]);
  __shared__ float red[256];
  red[t] = s;
  __syncthreads();
  if (t < 128) part[(size_t)(h * 8 + chunk) * 128 + d] = red[t] + red[t + 128];
}

__global__ __launch_bounds__(256) void vmean_i0(const float* __restrict__ part,
    const float* __restrict__ amask, const float* __restrict__ dmask,
    float* __restrict__ vmean, int* __restrict__ i0)
{
  const int h = blockIdx.x, t = threadIdx.x;
  if (t < 128) {
    float s = 0.f;
#pragma unroll
    for (int c = 0; c < 8; ++c) s += part[(size_t)(h * 8 + c) * 128 + t];
    vmean[h * 128 + t] = s * (1.f / 2048.f);
  }
  int best = 0x7fffffff;
  for (int j = t; j < 2048; j += 256) {
    if (amask[j] * dmask[h * 2048 + j] != 0.f) { best = j; break; }
  }
  __shared__ int red[256];
  red[t] = best;
  __syncthreads();
  for (int off = 128; off > 0; off >>= 1) {
    if (t < off) red[t] = min(red[t], red[t + off]);
    __syncthreads();
  }
  if (t == 0) i0[h] = red[0];
}

// ---------------------------------------------------------------------------
// MFMA flash attention (R16 config): stripe-paired, 8 waves = 2 k-parity
// groups x 4 row waves, double-buffered K/V LDS staging, XCD-swizzled grid,
// exp2 softmax, defer-max + MFMA-l. Measured 56.1 us.
// ---------------------------------------------------------------------------
#define QLD 4096
__global__ __launch_bounds__(512) void attn_mfma(
    const ushort* __restrict__ qb, const ushort* __restrict__ kb,
    const ushort* __restrict__ vt, const float* __restrict__ amask,
    const float* __restrict__ dmask, const float* __restrict__ vmean,
    const int* __restrict__ i0, ushort* __restrict__ ao)
{
  const int L  = blockIdx.x;
  const int pr = L >> 4;                               // pair 0..15
  const int h  = (L & 7) | (((L >> 3) & 1) << 3);      // head; L%8 == h%8
  const int t  = threadIdx.x, w = t >> 6, lane = t & 63;
  const int g  = w >> 2, wg = w & 3;
  const int lr = lane & 15, lk = lane >> 4;

  __shared__ char smem[155648];
  float* accL  = (float*)smem;                      // [64][132] f32 (merge)
  float* smv   = (float*)(smem + 33792);            // [2][64]
  float* slv   = (float*)(smem + 33792 + 512);      // [2][64]
  float* maddL = (float*)(smem + 147456);           // [2048]

  const int i0h = i0[h];

  bf16x8 onesb;
#pragma unroll
  for (int u = 0; u < 8; ++u) onesb[u] = (short)0x3F80;  // bf16 1.0

  for (int j = t; j < 2048; j += 512)
    maddL[j] = (amask[j] * dmask[h * 2048 + j] == 0.f) ? NEG_MIN : 0.f;

  for (int sp = 0; sp < 2; ++sp) {
    const int stripe = (sp == 0) ? pr : 31 - pr;
    const int q0 = stripe << 6;
    const int ntiles = stripe + 1;

    __syncthreads();

    const int qrow = q0 + wg * 16 + lr;
    bf16x8 qf[4];
#pragma unroll
    for (int kk = 0; kk < 4; ++kk)
      qf[kk] = *(const bf16x8*)(qb + (size_t)qrow * QLD + h * 128 + kk * 32 + lk * 8);

    if (g < ntiles) {
      const int c0 = g << 6;
#pragma unroll
      for (int qI = 0; qI < 4; ++qI) {
        int b = wg * 4096 + qI * 1024 + lane * 16;
        int row = b >> 8, colb = b & 255;
        int src = colb ^ ((row & 7) << 4);
        gload_lds16((const char*)kb + ((size_t)(c0 + row) * QLD + h * 128) * 2 + src,
                    smem + g * 32768 + b);
      }
#pragma unroll
      for (int qI = 0; qI < 4; ++qI) {
        int b = wg * 4096 + qI * 1024 + lane * 16;
        int row = b >> 7, colb = b & 127;
        int src = colb ^ ((row & 7) << 4);
        gload_lds16((const char*)vt + ((size_t)(h * 128 + row) * 2048 + c0) * 2 + src,
                    smem + 65536 + g * 32768 + b);
      }
    }

    float m[4];
    f32x4 acc_l = (f32x4){0.f, 0.f, 0.f, 0.f};
    f32x4 acc_o[8];
#pragma unroll
    for (int j = 0; j < 4; ++j) m[j] = -FLT_MAX;
#pragma unroll
    for (int ni = 0; ni < 8; ++ni) acc_o[ni] = (f32x4){0.f, 0.f, 0.f, 0.f};

    int cur = 0;
    const int niter = (ntiles + 1) >> 1;
    for (int it = 0; it < niter; ++it) {
      const int tile = 2 * it + g;
      const int c0 = tile << 6;
      __syncthreads();

      float madd[4];
      if (tile < ntiles) {
#pragma unroll
        for (int ni = 0; ni < 4; ++ni)
          madd[ni] = maddL[c0 + ni * 16 + lr];
      }

      if (tile + 2 < ntiles) {
        const int cn = c0 + 128;
        const int nb = cur ^ 1;
#pragma unroll
        for (int qI = 0; qI < 4; ++qI) {
          int b = wg * 4096 + qI * 1024 + lane * 16;
          int row = b >> 8, colb = b & 255;
          int src = colb ^ ((row & 7) << 4);
          gload_lds16((const char*)kb + ((size_t)(cn + row) * QLD + h * 128) * 2 + src,
                      smem + g * 32768 + nb * 16384 + b);
        }
#pragma unroll
        for (int qI = 0; qI < 4; ++qI) {
          int b = wg * 4096 + qI * 1024 + lane * 16;
          int row = b >> 7, colb = b & 127;
          int src = colb ^ ((row & 7) << 4);
          gload_lds16((const char*)vt + ((size_t)(h * 128 + row) * 2048 + cn) * 2 + src,
                      smem + 65536 + g * 32768 + nb * 16384 + b);
        }
      }

      if (tile < ntiles) {
        const bool diag = (tile == stripe);
        const char* Kbase = smem + g * 32768 + cur * 16384;
        const char* Vbase = smem + 65536 + g * 32768 + cur * 16384;
        char* Pbase = smem + 131072 + g * 8192;

        f32x4 sacc[4];
#pragma unroll
        for (int ni = 0; ni < 4; ++ni) sacc[ni] = (f32x4){0.f, 0.f, 0.f, 0.f};
        __builtin_amdgcn_s_setprio(1);
#pragma unroll
        for (int kk = 0; kk < 4; ++kk) {
#pragma unroll
          for (int ni = 0; ni < 4; ++ni) {
            int krow = ni * 16 + lr;
            bf16x8 bfr = *(const bf16x8*)(Kbase + krow * 256 + ((kk * 64 + lk * 16) ^ ((krow & 7) << 4)));
            sacc[ni] = __builtin_amdgcn_mfma_f32_16x16x32_bf16(qf[kk], bfr, sacc[ni], 0, 0, 0);
          }
        }
        __builtin_amdgcn_s_setprio(0);

        // ---- softmax: defer-max; l from MFMA ones-column (acc_l)
#pragma unroll
        for (int j = 0; j < 4; ++j) {
          int grow = q0 + wg * 16 + lk * 4 + j;
          float x[4];
#pragma unroll
          for (int ni = 0; ni < 4; ++ni) {
            float v = fmaf(sacc[ni][j], SCALE_L2E, madd[ni]);
            if (diag && c0 + ni * 16 + lr > grow) v = NEG_MIN;
            x[ni] = v;
          }
          float pm = fmaxf(fmaxf(x[0], x[1]), fmaxf(x[2], x[3]));
          if (!__all(pm <= m[j] + 16.f)) {
            float tmax = pm;
            tmax = fmaxf(tmax, dpp_ror<0x121>(tmax));
            tmax = fmaxf(tmax, dpp_ror<0x122>(tmax));
            tmax = fmaxf(tmax, dpp_ror<0x124>(tmax));
            tmax = fmaxf(tmax, dpp_ror<0x128>(tmax));
            float mn = fmaxf(m[j], tmax);
            if (mn > m[j]) {
              float sc = exp2f(m[j] - mn);
              acc_l[j] *= sc;
#pragma unroll
              for (int ni = 0; ni < 8; ++ni) acc_o[ni][j] *= sc;
              m[j] = mn;
            }
          }
          int prow = wg * 16 + lk * 4 + j;
#pragma unroll
          for (int ni = 0; ni < 4; ++ni) {
            float p = exp2f(x[ni] - m[j]);
            *(ushort*)(Pbase + prow * 128 + ((2 * (ni * 16 + lr)) ^ ((prow & 7) << 4))) = f2bf(p);
          }
        }

        __builtin_amdgcn_s_setprio(1);
#pragma unroll
        for (int kk = 0; kk < 2; ++kk) {
          int prow = wg * 16 + lr;
          bf16x8 a = *(const bf16x8*)(Pbase + prow * 128 + ((kk * 64 + lk * 16) ^ ((prow & 7) << 4)));
          acc_l = __builtin_amdgcn_mfma_f32_16x16x32_bf16(a, onesb, acc_l, 0, 0, 0);
#pragma unroll
          for (int ni = 0; ni < 8; ++ni) {
            int vrow = ni * 16 + lr;
            bf16x8 bfr = *(const bf16x8*)(Vbase + vrow * 128 + ((kk * 64 + lk * 16) ^ ((vrow & 7) << 4)));
            acc_o[ni] = __builtin_amdgcn_mfma_f32_16x16x32_bf16(a, bfr, acc_o[ni], 0, 0, 0);
          }
        }
        __builtin_amdgcn_s_setprio(0);
      }
      cur ^= 1;
    }

    __syncthreads();
    if (lr == 0) {
#pragma unroll
      for (int j = 0; j < 4; ++j) {
        int r = wg * 16 + lk * 4 + j;
        smv[g * 64 + r] = m[j];
        slv[g * 64 + r] = acc_l[j];
      }
    }
    __syncthreads();
    float myf[4], lcomb[4];
#pragma unroll
    for (int j = 0; j < 4; ++j) {
      int r = wg * 16 + lk * 4 + j;
      float m0 = smv[r], m1 = smv[64 + r];
      float l0 = slv[r], l1 = slv[64 + r];
      float mm = fmaxf(m0, m1);
      float f0 = exp2f(m0 - mm), f1 = exp2f(m1 - mm);
      lcomb[j] = l0 * f0 + l1 * f1;
      myf[j] = (g == 0) ? f0 : f1;
    }
    if (g == 1) {
#pragma unroll
      for (int j = 0; j < 4; ++j) {
        int r = wg * 16 + lk * 4 + j;
#pragma unroll
        for (int ni = 0; ni < 8; ++ni)
          accL[r * 132 + ni * 16 + lr] = acc_o[ni][j] * myf[j];
      }
    }
    __syncthreads();
    if (g == 0) {
#pragma unroll
      for (int j = 0; j < 4; ++j) {
        int row = q0 + wg * 16 + lk * 4 + j;
        int r = wg * 16 + lk * 4 + j;
        if (row < i0h) {
#pragma unroll
          for (int ni = 0; ni < 8; ++ni)
            ao[(size_t)row * 2048 + h * 128 + ni * 16 + lr] = f2bf(vmean[h * 128 + ni * 16 + lr]);
        } else {
          float inv = 1.f / lcomb[j];
#pragma unroll
          for (int ni = 0; ni < 8; ++ni) {
            float o = fmaf(acc_o[ni][j], myf[j], accL[r * 132 + ni * 16 + lr]);
            ao[(size_t)row * 2048 + h * 128 + ni * 16 + lr] = f2bf(o * inv);
          }
        }
      }
    }
  }
}

// ---------------------------------------------------------------------------
extern "C" void kernel_launch(void* const* d_in, const int* in_sizes, int n_in,
                              void* d_out, int out_size, void* d_ws, size_t ws_size,
                              hipStream_t stream)
{
  const float* hs    = (const float*)d_in[0];
  const float* amask = (const float*)d_in[1];
  const float* cosb  = (const float*)d_in[2];
  const float* sinb  = (const float*)d_in[3];
  const float* dmask = (const float*)d_in[4];
  const float* Wq    = (const float*)d_in[5];
  const float* Wk    = (const float*)d_in[6];
  const float* Wvq   = (const float*)d_in[7];
  const float* vkeys = (const float*)d_in[8];
  const float* vemb  = (const float*)d_in[9];
  const float* Wo    = (const float*)d_in[10];
  float* outp = (float*)d_out;

  char* ws = (char*)d_ws;
  const size_t MB = 1048576;
  float*  pvq     = (float*) (ws + 0);              // A: [0,32) 8 partials
  ushort* WvqTh   = (ushort*)(ws + 32*MB);          // A: [32,34)
  ushort* WvqTl   = (ushort*)(ws + 34*MB);          // A: [34,36)
  ushort* hs_lo   = (ushort*)(ws + 55*MB);          // A: [55,63)
  float*  vq_f32  = (float*) (ws + 64*MB);          // A-B: [64,68)
  ushort* vq_bf   = (ushort*)(ws + 68*MB);          // A-B: [68,70)
  ushort* vkT     = (ushort*)(ws + 0);              // B: [0,2)   over dead pvq
  ushort* sim_bf  = (ushort*)(ws + 2*MB);           // B: [2,34)
  int*    idx     = (int*)   (ws + 34*MB);          // B-C: 128 KB
  float*  vkTf32  = (float*) (ws + 36*MB);          // B: [36,40)
  ushort* vemb_bf = (ushort*)(ws + 70*MB);          // A-C: [70,78)
  ushort* hs_bf   = (ushort*)(ws + 43*MB);          // A-D: [43,51)
  ushort* vb      = (ushort*)(ws + 0);              // C: [0,8)
  ushort* vt      = (ushort*)(ws + 8*MB);           // C-E: [8,16)
  float*  part    = (float*) (ws + 51*MB);          // C: 64 KB
  float*  vmean   = (float*) (ws + 51*MB + 65536);  // C-E: 8 KB
  int*    i0b     = (int*)   (ws + 51*MB + 73728);  // C-E: 64 B
  ushort* WBig    = (ushort*)(ws + 16*MB);          // D-E: [16,40) Wq|Wk|Wo^T
  ushort* WoT     = (ushort*)(ws + 32*MB);          // = WBig + 16MB
  ushort* qkC     = (ushort*)(ws + 52*MB);          // D-E: [52,68) q|k, ld 4096
  ushort* ao      = (ushort*)(ws + 0);              // E: [0,8)

  dim3 blk(256);
  // ---- prep: conversions + Wvq hi/lo transpose ----
  cvt3_bf16<<<dim3(8192), blk, 0, stream>>>(vemb, vemb_bf, hs, hs_bf, hs_lo);
  transpose_cvt_hl<<<dim3(8, 32), blk, 0, stream>>>(Wvq, WvqTh, WvqTl);
  // ---- routing path: vq via 3-term bf16 MFMA emulation ----
  gemm_vq3<<<dim3(4, 16, 8), blk, 0, stream>>>(hs_bf, hs_lo, 2048,
      WvqTh, WvqTl, 2048, pvq, 512, 256);
  reduce8_cvt<<<dim3(1024), blk, 0, stream>>>(pvq, vq_f32, vq_bf);
  transpose_cvt_vk<<<dim3(32, 2, 4), blk, 0, stream>>>(vkeys, vkT, vkTf32);
  gemm_bf16<1, 0><<<dim3(16, 16, 4), blk, 0, stream>>>(vq_bf, 512, vkT, 128,
      sim_bf, 2048, 128, 128, 262144, 4194304, nullptr, nullptr);
  topk_sel<<<dim3(2048), blk, 0, stream>>>(sim_bf, vq_f32, vkTf32, idx);
  // ---- v construction ----
  gather_mul_bf<<<dim3(2048), blk, 0, stream>>>(hs, vemb_bf, idx, vb);
  transpose_bf<<<dim3(32, 32), blk, 0, stream>>>(vb, vt);
  vmean_part<<<dim3(8, 16), blk, 0, stream>>>(vb, part);
  vmean_i0<<<dim3(16), blk, 0, stream>>>(part, amask, dmask, vmean, i0b);
  // ---- projections: Wq|Wk|Wo transpose (z=3), fused qk GEMM + RoPE ----
  transpose_cvt_w3<<<dim3(32, 32, 3), blk, 0, stream>>>(Wq, Wk, Wo, WBig);
  gemm_bf16<1, 1><<<dim3(32, 16, 1), blk, 0, stream>>>(hs_bf, 2048, WBig, 2048,
      qkC, 4096, 2048, 0, 0, 0, cosb, sinb);
  // ---- attention (XCD-swizzled 1D grid) ----
  attn_mfma<<<dim3(256), dim3(512), 0, stream>>>(qkC, qkC + 2048, vt, amask, dmask, vmean, i0b, ao);
  // ---- output projection (128x64 tiles: 512 blocks = 2-3 blocks/CU) ----
  gemm_bf16_n64<<<dim3(32, 16), blk, 0, stream>>>(ao, 2048, WoT, 2048, outp, 2048, 2048);
}